// Round 8
// baseline (269.487 us; speedup 1.0000x reference)
//
#include <hip/hip_runtime.h>
#include <hip/hip_bf16.h>

#define B_ 2
#define S_ 2048
#define H_ 1024
#define NH_ 16
#define HD_ 64
#define M_ (B_*S_)   // 4096 rows

typedef __attribute__((ext_vector_type(8))) short bf16x8;
typedef __attribute__((ext_vector_type(4))) short bf16x4;
typedef __attribute__((ext_vector_type(4))) float f32x4;
typedef __attribute__((ext_vector_type(4))) int   i32x4;

// ---------------- helpers ----------------
__device__ inline float waveReduceSum(float v) {
#pragma unroll
  for (int off = 32; off >= 1; off >>= 1) v += __shfl_xor(v, off);
  return v;
}

__device__ inline short f2bf(float f) {
  union { float f; unsigned u; } v; v.f = f;
  unsigned r = v.u + 0x7fffu + ((v.u >> 16) & 1u);  // RNE
  return (short)(r >> 16);
}

__device__ inline unsigned cvt_pk_bf16(float lo, float hi) {
  unsigned w;
  asm("v_cvt_pk_bf16_f32 %0, %1, %2" : "=v"(w) : "v"(lo), "v"(hi));
  return w;
}

__device__ inline void async_load16(const void* g, void* l) {
  __builtin_amdgcn_global_load_lds(
      (const __attribute__((address_space(1))) void*)g,
      (__attribute__((address_space(3))) void*)l, 16, 0, 0);
}

// 16B-chunk swizzle within a 128B LDS row (8 chunks); row in [0,64)
__device__ inline int swz8(int r) { return (r & 3) | (((r >> 3) & 1) << 2); }

// ---------------- fp32 -> bf16 convert (X) ----------------
__global__ __launch_bounds__(256)
void cvt_bf16(const float* __restrict__ in, short* __restrict__ out) {
  const size_t i = (size_t)blockIdx.x * 256 + threadIdx.x;
  float4 v = ((const float4*)in)[i];
  bf16x4 o;
  o[0] = f2bf(v.x); o[1] = f2bf(v.y); o[2] = f2bf(v.z); o[3] = f2bf(v.w);
  ((bf16x4*)out)[i] = o;
}

// ---------------- W[k][n] fp32 -> Wt[n][k] bf16 (QKV packed + O) ----------------
__global__ __launch_bounds__(256)
void transpose_w4(const float* __restrict__ W0, const float* __restrict__ W1,
                  const float* __restrict__ W2, const float* __restrict__ W3,
                  short* __restrict__ Tqkv, short* __restrict__ To) {
  const float* W; short* T;
  switch (blockIdx.z) {
    case 0: W = W0; T = Tqkv; break;
    case 1: W = W1; T = Tqkv + (size_t)1024 * 1024; break;
    case 2: W = W2; T = Tqkv + (size_t)2048 * 1024; break;
    default: W = W3; T = To; break;
  }
  __shared__ float tile[32][36];
  const int tid = threadIdx.x;
  const int tx = tid & 7, ty = tid >> 3;
  const int k0 = blockIdx.y << 5, n0 = blockIdx.x << 5;
  float4 v = *(const float4*)&W[(size_t)(k0 + ty) * H_ + n0 + (tx << 2)];
  tile[ty][(tx << 2) + 0] = v.x;
  tile[ty][(tx << 2) + 1] = v.y;
  tile[ty][(tx << 2) + 2] = v.z;
  tile[ty][(tx << 2) + 3] = v.w;
  __syncthreads();
  bf16x4 o;
  o[0] = f2bf(tile[(tx << 2) + 0][ty]);
  o[1] = f2bf(tile[(tx << 2) + 1][ty]);
  o[2] = f2bf(tile[(tx << 2) + 2][ty]);
  o[3] = f2bf(tile[(tx << 2) + 3][ty]);
  *(bf16x4*)&T[(size_t)(n0 + ty) * H_ + k0 + (tx << 2)] = o;
}

// ---------------- fused QKV GEMM: [4096,1024] @ [1024,3072] ----------------
// Q (n<1024): bf16 head layout, pre-scaled by 0.125*log2(e)  (exp2-domain scores)
// K: bf16 head layout. V: bf16 transposed [bh][d][S].
__global__ __launch_bounds__(256)
void gemm_qkv(const short* __restrict__ A, const short* __restrict__ Bt,
              const float* __restrict__ bq, const float* __restrict__ bk,
              const float* __restrict__ bv, short* __restrict__ Qo,
              short* __restrict__ Ko, short* __restrict__ Vto) {
  __shared__ short A_lds[2][128][32];
  __shared__ short B_lds[2][128][32];
  const int tid = threadIdx.x;
  const int lane = tid & 63, wv = tid >> 6;
  const int l16 = lane & 15, lg = lane >> 4;
  const int wr = wv >> 1, wc = wv & 1;
  const int swzb = (blockIdx.x & 7) * 96 + (blockIdx.x >> 3);
  const int bx = swzb % 24, by = swzb / 24;
  const int m0 = by << 7, n0 = bx << 7;
  const int K = H_;

  const int srow = lane >> 2, soff = (lane & 3) << 3;

  f32x4 acc[4][4] = {};

#pragma unroll
  for (int i = 0; i < 2; ++i) {
    const int c = 2 * wv + i;
    async_load16(A + (size_t)(m0 + 16 * c + srow) * K + soff, &A_lds[0][16 * c][0]);
    async_load16(Bt + (size_t)(n0 + 16 * c + srow) * K + soff, &B_lds[0][16 * c][0]);
  }

  int cur = 0;
  for (int t = 0; t < K / 32; ++t) {
    __syncthreads();
    if (t + 1 < K / 32) {
      const int k0 = (t + 1) << 5;
#pragma unroll
      for (int i = 0; i < 2; ++i) {
        const int c = 2 * wv + i;
        async_load16(A + (size_t)(m0 + 16 * c + srow) * K + k0 + soff,
                     &A_lds[cur ^ 1][16 * c][0]);
        async_load16(Bt + (size_t)(n0 + 16 * c + srow) * K + k0 + soff,
                     &B_lds[cur ^ 1][16 * c][0]);
      }
    }
    bf16x8 af[4], bfr[4];
#pragma unroll
    for (int i = 0; i < 4; ++i)
      af[i] = *(const bf16x8*)&A_lds[cur][64 * wr + 16 * i + l16][8 * lg];
#pragma unroll
    for (int j = 0; j < 4; ++j)
      bfr[j] = *(const bf16x8*)&B_lds[cur][64 * wc + 16 * j + l16][8 * lg];
#pragma unroll
    for (int i = 0; i < 4; ++i)
#pragma unroll
      for (int j = 0; j < 4; ++j)
        acc[i][j] = __builtin_amdgcn_mfma_f32_16x16x32_bf16(af[i], bfr[j], acc[i][j], 0, 0, 0);
    cur ^= 1;
  }

  const int mt = n0 >> 10;  // 0=Q 1=K 2=V (uniform per block)
  const float* bias = (mt == 0) ? bq : (mt == 1 ? bk : bv);
  const float qs = (mt == 0) ? 0.125f * 1.4426950408889634f : 1.0f;

  if (mt < 2) {
    short* Out = (mt == 0) ? Qo : Ko;
#pragma unroll
    for (int i = 0; i < 4; ++i) {
#pragma unroll
      for (int j = 0; j < 4; ++j) {
        const int nl = (n0 & 1023) + 64 * wc + 16 * j + l16;
        const float bvl = bias[nl];
        const int h = nl >> 6, d = nl & 63;
#pragma unroll
        for (int r = 0; r < 4; ++r) {
          const int m = m0 + 64 * wr + 16 * i + 4 * lg + r;
          const int b = m >> 11, s = m & (S_ - 1);
          Out[(((size_t)(b * NH_ + h) * S_ + s) << 6) + d] =
              f2bf((acc[i][j][r] + bvl) * qs);
        }
      }
    }
  } else {
#pragma unroll
    for (int i = 0; i < 4; ++i) {
      const int mb = m0 + 64 * wr + 16 * i + 4 * lg;
      const int b = mb >> 11, s = mb & (S_ - 1);
#pragma unroll
      for (int j = 0; j < 4; ++j) {
        const int nl = (n0 & 1023) + 64 * wc + 16 * j + l16;
        const float bvl = bias[nl];
        const int h = nl >> 6, d = nl & 63;
        bf16x4 pk;
#pragma unroll
        for (int r = 0; r < 4; ++r) pk[r] = f2bf(acc[i][j][r] + bvl);
        *(bf16x4*)&Vto[(((size_t)(b * NH_ + h) * HD_ + d) << 11) + s] = pk;
      }
    }
  }
}

// ---------------- O-projection GEMM: ctx_bf16 [M][1024] @ Wto^T -> fp32 ----------------
__global__ __launch_bounds__(256)
void gemm_o(const short* __restrict__ A, const short* __restrict__ Bt,
            const float* __restrict__ bias, float* __restrict__ C) {
  __shared__ short A_lds[2][128][32];
  __shared__ short B_lds[2][128][32];
  const int tid = threadIdx.x;
  const int lane = tid & 63, wv = tid >> 6;
  const int l16 = lane & 15, lg = lane >> 4;
  const int wr = wv >> 1, wc = wv & 1;
  const int swzb = (blockIdx.x & 7) * 32 + (blockIdx.x >> 3);
  const int bx = swzb & 7, by = swzb >> 3;
  const int m0 = by << 7, n0 = bx << 7;
  const int K = H_;

  const int srow = lane >> 2, soff = (lane & 3) << 3;

  f32x4 acc[4][4] = {};

#pragma unroll
  for (int i = 0; i < 2; ++i) {
    const int c = 2 * wv + i;
    async_load16(A + (size_t)(m0 + 16 * c + srow) * K + soff, &A_lds[0][16 * c][0]);
    async_load16(Bt + (size_t)(n0 + 16 * c + srow) * K + soff, &B_lds[0][16 * c][0]);
  }

  int cur = 0;
  for (int t = 0; t < K / 32; ++t) {
    __syncthreads();
    if (t + 1 < K / 32) {
      const int k0 = (t + 1) << 5;
#pragma unroll
      for (int i = 0; i < 2; ++i) {
        const int c = 2 * wv + i;
        async_load16(A + (size_t)(m0 + 16 * c + srow) * K + k0 + soff,
                     &A_lds[cur ^ 1][16 * c][0]);
        async_load16(Bt + (size_t)(n0 + 16 * c + srow) * K + k0 + soff,
                     &B_lds[cur ^ 1][16 * c][0]);
      }
    }
    bf16x8 af[4], bfr[4];
#pragma unroll
    for (int i = 0; i < 4; ++i)
      af[i] = *(const bf16x8*)&A_lds[cur][64 * wr + 16 * i + l16][8 * lg];
#pragma unroll
    for (int j = 0; j < 4; ++j)
      bfr[j] = *(const bf16x8*)&B_lds[cur][64 * wc + 16 * j + l16][8 * lg];
#pragma unroll
    for (int i = 0; i < 4; ++i)
#pragma unroll
      for (int j = 0; j < 4; ++j)
        acc[i][j] = __builtin_amdgcn_mfma_f32_16x16x32_bf16(af[i], bfr[j], acc[i][j], 0, 0, 0);
    cur ^= 1;
  }

#pragma unroll
  for (int i = 0; i < 4; ++i)
#pragma unroll
    for (int j = 0; j < 4; ++j) {
      const int n = n0 + 64 * wc + 16 * j + l16;
      const float bvl = bias[n];
#pragma unroll
      for (int r = 0; r < 4; ++r) {
        const int m = m0 + 64 * wr + 16 * i + 4 * lg + r;
        C[(size_t)m * H_ + n] = acc[i][j][r] + bvl;
      }
    }
}

// ---------------- Flash attention: swapped QK^T, in-register P, DMA staging ----------------
// Q,K bf16 [bh][s][64] (Q pre-scaled by 0.125*log2e); Vt bf16 [bh][d][S];
// ctx bf16 [B,S,NH,HD]. Scores in exp2 domain. LDS linear [64][64] with
// 16B-chunk XOR swizzle applied to the DMA *source* and the *read* address
// (rule #21: both-sides-or-neither). Defer-max (T13, THR=8).
#define KVB 64

__global__ __launch_bounds__(256)
void attn_mfma(const short* __restrict__ Qg, const short* __restrict__ Kg,
               const short* __restrict__ Vtg, short* __restrict__ ctxb) {
  __shared__ short K_lds[2][KVB][64];  // [kv][d], swizzled content
  __shared__ short V_t[2][KVB][64];    // [d][kv], swizzled content

  const int tid  = threadIdx.x;
  const int lane = tid & 63;
  const int wv   = tid >> 6;
  const int l16  = lane & 15, lg = lane >> 4;

  // XCD swizzle: 1024 blocks -> 128 consecutive per XCD
  const int swz = (blockIdx.x & 7) * 128 + (blockIdx.x >> 3);
  const int bh = swz >> 5, qb = swz & 31;

  const short* Qh = Qg + ((size_t)bh * S_ << 6);
  const short* Kh = Kg + ((size_t)bh * S_ << 6);
  const short* Vh = Vtg + ((size_t)bh << 6) * S_;  // [64][2048]

  const int q0 = qb * 64 + wv * 16;

  bf16x8 qf[2];
  qf[0] = *(const bf16x8*)&Qh[((size_t)(q0 + l16) << 6) + 8 * lg];
  qf[1] = *(const bf16x8*)&Qh[((size_t)(q0 + l16) << 6) + 8 * lg + 32];

  const int l16part = ((l16 >> 2) << 3) + (l16 & 3);  // K-row remap, lane part

  // staging lane mapping: wave wv covers rows [16wv,16wv+16), 2 issues of 8 rows
  const int srow8 = lane >> 3;        // row within 8-row chunk
  const int schk  = lane & 7;         // 16B chunk within 128B row

  f32x4 o[4] = {};
  float m_run = -1e30f, l_run = 0.f;  // stats for q-row l16 (replicated over lg)

#define STAGE(buf, kv0)                                                        \
  {                                                                            \
    _Pragma("unroll")                                                          \
    for (int i_ = 0; i_ < 2; ++i_) {                                           \
      const int row_ = 16 * wv + 8 * i_ + srow8;                               \
      const int ch_ = schk ^ swz8(row_);                                       \
      async_load16(Kh + (((size_t)((kv0) + row_)) << 6) + (ch_ << 3),          \
                   &K_lds[buf][16 * wv + 8 * i_][0]);                          \
      async_load16(Vh + (size_t)row_ * S_ + (kv0) + (ch_ << 3),                \
                   &V_t[buf][16 * wv + 8 * i_][0]);                            \
    }                                                                          \
  }

  STAGE(0, 0)  // prologue

  int cur = 0;
  for (int t = 0; t < S_ / KVB; ++t) {
    __syncthreads();  // drains vmcnt: buf[cur] staged; buf[cur^1] readers done
    if (t + 1 < S_ / KVB) STAGE(cur ^ 1, (t + 1) * KVB)

    // swapped QK^T with row-remap: s[tt] elem r holds
    // S2[kv = 32*(tt>>1) + 8*lg + 4*(tt&1) + r][q = l16]  (exp2 domain)
    f32x4 s[4] = {};
#pragma unroll
    for (int ks = 0; ks < 2; ++ks)
#pragma unroll
      for (int tt = 0; tt < 4; ++tt) {
        const int krow = ((tt >> 1) << 5) + ((tt & 1) << 2) + l16part;
        const int kch = (lg + 4 * ks) ^ swz8(krow);
        bf16x8 kf = *(const bf16x8*)&K_lds[cur][krow][kch << 3];
        s[tt] = __builtin_amdgcn_mfma_f32_16x16x32_bf16(kf, qf[ks], s[tt], 0, 0, 0);
      }

    // tile max for q=l16: in-lane 16 + xor over lanes 16,32
    float pmax = fmaxf(fmaxf(fmaxf(s[0][0], s[0][1]), fmaxf(s[0][2], s[0][3])),
                       fmaxf(fmaxf(s[1][0], s[1][1]), fmaxf(s[1][2], s[1][3])));
    pmax = fmaxf(pmax,
                 fmaxf(fmaxf(fmaxf(s[2][0], s[2][1]), fmaxf(s[2][2], s[2][3])),
                       fmaxf(fmaxf(s[3][0], s[3][1]), fmaxf(s[3][2], s[3][3]))));
    pmax = fmaxf(pmax, __shfl_xor(pmax, 16));
    pmax = fmaxf(pmax, __shfl_xor(pmax, 32));

    float p[4][4];
    float rs = 0.f;
    if (__any(pmax - m_run > 8.0f)) {   // rescale path (rare after warmup)
      const float mn = fmaxf(m_run, pmax);
      const float scl = __builtin_amdgcn_exp2f(m_run - mn);
      m_run = mn;
#pragma unroll
      for (int tt = 0; tt < 4; ++tt)
#pragma unroll
        for (int r = 0; r < 4; ++r) {
          p[tt][r] = __builtin_amdgcn_exp2f(s[tt][r] - mn);
          rs += p[tt][r];
        }
      rs += __shfl_xor(rs, 16);
      rs += __shfl_xor(rs, 32);
      l_run = l_run * scl + rs;
      float sclr[4];
#pragma unroll
      for (int r = 0; r < 4; ++r) sclr[r] = __shfl(scl, 4 * lg + r);
#pragma unroll
      for (int tt = 0; tt < 4; ++tt)
#pragma unroll
        for (int r = 0; r < 4; ++r) o[tt][r] *= sclr[r];
    } else {                            // defer path: P <= 2^8, no o-rescale
#pragma unroll
      for (int tt = 0; tt < 4; ++tt)
#pragma unroll
        for (int r = 0; r < 4; ++r) {
          p[tt][r] = __builtin_amdgcn_exp2f(s[tt][r] - m_run);
          rs += p[tt][r];
        }
      rs += __shfl_xor(rs, 16);
      rs += __shfl_xor(rs, 32);
      l_run += rs;
    }

    // pack P to bf16 (lane-local PV A-fragments)
    unsigned w[4][2];
#pragma unroll
    for (int tt = 0; tt < 4; ++tt) {
      w[tt][0] = cvt_pk_bf16(p[tt][0], p[tt][1]);
      w[tt][1] = cvt_pk_bf16(p[tt][2], p[tt][3]);
    }

    // PV: A = P (in-register), B = V^T rows (swizzled b128 reads)
#pragma unroll
    for (int ks = 0; ks < 2; ++ks) {
      i32x4 aw;
      aw[0] = (int)w[2 * ks][0];
      aw[1] = (int)w[2 * ks][1];
      aw[2] = (int)w[2 * ks + 1][0];
      aw[3] = (int)w[2 * ks + 1][1];
      const bf16x8 pf = __builtin_bit_cast(bf16x8, aw);
#pragma unroll
      for (int tt = 0; tt < 4; ++tt) {
        const int vrow = 16 * tt + l16;
        const int vch = (lg + 4 * ks) ^ swz8(vrow);
        bf16x8 vf = *(const bf16x8*)&V_t[cur][vrow][vch << 3];
        o[tt] = __builtin_amdgcn_mfma_f32_16x16x32_bf16(pf, vf, o[tt], 0, 0, 0);
      }
    }
    cur ^= 1;
  }
#undef STAGE

  // epilogue: ctx[b][s][h*64+d] bf16; rows q = 4lg+r, cols d = 16tt+l16
  float invr[4];
#pragma unroll
  for (int r = 0; r < 4; ++r) invr[r] = 1.f / __shfl(l_run, 4 * lg + r);
  const int b = bh >> 4, h = bh & 15;
#pragma unroll
  for (int r = 0; r < 4; ++r) {
    const int q = q0 + 4 * lg + r;
#pragma unroll
    for (int tt = 0; tt < 4; ++tt)
      ctxb[(((size_t)(b * S_ + q) * NH_ + h) << 6) + 16 * tt + l16] =
          f2bf(o[tt][r] * invr[r]);
  }
}

// ---------------- residual + LayerNorm ----------------
__global__ __launch_bounds__(256)
void resid_ln(const float* __restrict__ attn_out, const float* __restrict__ hs,
              const float* __restrict__ gamma, const float* __restrict__ beta,
              float* __restrict__ out) {
  __shared__ float reds[4], reds2[4];
  const int row = blockIdx.x;
  const int tid = threadIdx.x;
  const float4* a4 = (const float4*)(attn_out + ((size_t)row << 10));
  const float4* h4 = (const float4*)(hs + ((size_t)row << 10));
  float4 a = a4[tid], h = h4[tid];
  float e0 = a.x + h.x, e1 = a.y + h.y, e2 = a.z + h.z, e3 = a.w + h.w;
  float s  = e0 + e1 + e2 + e3;
  float sq = e0 * e0 + e1 * e1 + e2 * e2 + e3 * e3;
  s = waveReduceSum(s);
  sq = waveReduceSum(sq);
  const int lane = tid & 63, wave = tid >> 6;
  if (lane == 0) { reds[wave] = s; reds2[wave] = sq; }
  __syncthreads();
  const float S1 = reds[0] + reds[1] + reds[2] + reds[3];
  const float S2 = reds2[0] + reds2[1] + reds2[2] + reds2[3];
  const float mu = S1 * (1.f / H_);
  const float var = S2 * (1.f / H_) - mu * mu;
  const float rstd = rsqrtf(var + 1e-12f);
  const float4 g = ((const float4*)gamma)[tid];
  const float4 bb = ((const float4*)beta)[tid];
  float4 o;
  o.x = (e0 - mu) * rstd * g.x + bb.x;
  o.y = (e1 - mu) * rstd * g.y + bb.y;
  o.z = (e2 - mu) * rstd * g.z + bb.z;
  o.w = (e3 - mu) * rstd * g.w + bb.w;
  ((float4*)(out + ((size_t)row << 10)))[tid] = o;
}

extern "C" void kernel_launch(void* const* d_in, const int* in_sizes, int n_in,
                              void* d_out, int out_size, void* d_ws, size_t ws_size,
                              hipStream_t stream) {
  const float* X     = (const float*)d_in[0];
  const float* Wq    = (const float*)d_in[1];
  const float* bq    = (const float*)d_in[2];
  const float* Wk    = (const float*)d_in[3];
  const float* bk    = (const float*)d_in[4];
  const float* Wv    = (const float*)d_in[5];
  const float* bv    = (const float*)d_in[6];
  const float* Wo    = (const float*)d_in[7];
  const float* bo    = (const float*)d_in[8];
  const float* gamma = (const float*)d_in[9];
  const float* beta  = (const float*)d_in[10];
  float* out = (float*)d_out;

  // workspace layout (peak 40 MB)
  char* ws = (char*)d_ws;
  short* Xbf  = (short*)ws;                        // 8 MB [M][H] bf16
  short* Wqkv = (short*)(ws + ( 8u << 20));        // 6 MB [3072][1024] bf16
  short* Wto  = (short*)(ws + (14u << 20));        // 2 MB [1024][1024] bf16
  short* Qbf  = (short*)(ws + (16u << 20));        // 8 MB [bh][s][64] (pre-scaled)
  short* Kbf  = (short*)(ws + (24u << 20));        // 8 MB [bh][s][64]
  short* Vt   = (short*)(ws + (32u << 20));        // 8 MB [bh][d][S] (transposed)
  short* ctxb = Xbf;                               // ctx bf16 overwrites Xbf (dead)
  float* attn = (float*)(ws + (16u << 20));        // fp32, overwrites Q/K (dead)

  dim3 blk(256);
  hipLaunchKernelGGL(cvt_bf16, dim3((M_ * H_) / 1024), blk, 0, stream, X, Xbf);
  hipLaunchKernelGGL(transpose_w4, dim3(32, 32, 4), blk, 0, stream,
                     Wq, Wk, Wv, Wo, Wqkv, Wto);
  hipLaunchKernelGGL(gemm_qkv, dim3(768), blk, 0, stream,
                     Xbf, Wqkv, bq, bk, bv, Qbf, Kbf, Vt);
  hipLaunchKernelGGL(attn_mfma, dim3(1024), blk, 0, stream, Qbf, Kbf, Vt, ctxb);
  hipLaunchKernelGGL(gemm_o, dim3(256), blk, 0, stream, ctxb, Wto, bo, attn);
  hipLaunchKernelGGL(resid_ln, dim3(M_), blk, 0, stream, attn, X, gamma, beta, out);
}

// Round 10
// 256.431 us; speedup vs baseline: 1.0509x; 1.0509x over previous
//
#include <hip/hip_runtime.h>
#include <hip/hip_bf16.h>

#define B_ 2
#define S_ 2048
#define H_ 1024
#define NH_ 16
#define HD_ 64
#define M_ (B_*S_)   // 4096 rows

typedef __attribute__((ext_vector_type(8))) short bf16x8;
typedef __attribute__((ext_vector_type(4))) short bf16x4;
typedef __attribute__((ext_vector_type(4))) float f32x4;
typedef __attribute__((ext_vector_type(4))) int   i32x4;

// ---------------- helpers ----------------
__device__ inline float waveReduceSum(float v) {
#pragma unroll
  for (int off = 32; off >= 1; off >>= 1) v += __shfl_xor(v, off);
  return v;
}

__device__ inline short f2bf(float f) {
  union { float f; unsigned u; } v; v.f = f;
  unsigned r = v.u + 0x7fffu + ((v.u >> 16) & 1u);  // RNE
  return (short)(r >> 16);
}

__device__ inline unsigned cvt_pk_bf16(float lo, float hi) {
  unsigned w;
  asm("v_cvt_pk_bf16_f32 %0, %1, %2" : "=v"(w) : "v"(lo), "v"(hi));
  return w;
}

__device__ inline void async_load16(const void* g, void* l) {
  __builtin_amdgcn_global_load_lds(
      (const __attribute__((address_space(1))) void*)g,
      (__attribute__((address_space(3))) void*)l, 16, 0, 0);
}

// 16B-chunk swizzle within a 128B LDS row (8 chunks); row in [0,64)
__device__ inline int swz8(int r) { return (r & 3) | (((r >> 3) & 1) << 2); }

// ---------------- fp32 -> bf16 convert (X) ----------------
__global__ __launch_bounds__(256)
void cvt_bf16(const float* __restrict__ in, short* __restrict__ out) {
  const size_t i = (size_t)blockIdx.x * 256 + threadIdx.x;
  float4 v = ((const float4*)in)[i];
  bf16x4 o;
  o[0] = f2bf(v.x); o[1] = f2bf(v.y); o[2] = f2bf(v.z); o[3] = f2bf(v.w);
  ((bf16x4*)out)[i] = o;
}

// ---------------- W[k][n] fp32 -> Wt[n][k] bf16 (QKV packed + O) ----------------
__global__ __launch_bounds__(256)
void transpose_w4(const float* __restrict__ W0, const float* __restrict__ W1,
                  const float* __restrict__ W2, const float* __restrict__ W3,
                  short* __restrict__ Tqkv, short* __restrict__ To) {
  const float* W; short* T;
  switch (blockIdx.z) {
    case 0: W = W0; T = Tqkv; break;
    case 1: W = W1; T = Tqkv + (size_t)1024 * 1024; break;
    case 2: W = W2; T = Tqkv + (size_t)2048 * 1024; break;
    default: W = W3; T = To; break;
  }
  __shared__ float tile[32][36];
  const int tid = threadIdx.x;
  const int tx = tid & 7, ty = tid >> 3;
  const int k0 = blockIdx.y << 5, n0 = blockIdx.x << 5;
  float4 v = *(const float4*)&W[(size_t)(k0 + ty) * H_ + n0 + (tx << 2)];
  tile[ty][(tx << 2) + 0] = v.x;
  tile[ty][(tx << 2) + 1] = v.y;
  tile[ty][(tx << 2) + 2] = v.z;
  tile[ty][(tx << 2) + 3] = v.w;
  __syncthreads();
  bf16x4 o;
  o[0] = f2bf(tile[(tx << 2) + 0][ty]);
  o[1] = f2bf(tile[(tx << 2) + 1][ty]);
  o[2] = f2bf(tile[(tx << 2) + 2][ty]);
  o[3] = f2bf(tile[(tx << 2) + 3][ty]);
  *(bf16x4*)&T[(size_t)(n0 + ty) * H_ + k0 + (tx << 2)] = o;
}

// ---------------- fused QKV GEMM: [4096,1024] @ [1024,3072] ----------------
// Q (n<1024): bf16 head layout, pre-scaled by 0.125*log2(e)  (exp2-domain scores)
// K: bf16 head layout. V: bf16 transposed [bh][d][S].
__global__ __launch_bounds__(256)
void gemm_qkv(const short* __restrict__ A, const short* __restrict__ Bt,
              const float* __restrict__ bq, const float* __restrict__ bk,
              const float* __restrict__ bv, short* __restrict__ Qo,
              short* __restrict__ Ko, short* __restrict__ Vto) {
  __shared__ short A_lds[2][128][32];
  __shared__ short B_lds[2][128][32];
  const int tid = threadIdx.x;
  const int lane = tid & 63, wv = tid >> 6;
  const int l16 = lane & 15, lg = lane >> 4;
  const int wr = wv >> 1, wc = wv & 1;
  const int swzb = (blockIdx.x & 7) * 96 + (blockIdx.x >> 3);
  const int bx = swzb % 24, by = swzb / 24;
  const int m0 = by << 7, n0 = bx << 7;
  const int K = H_;

  const int srow = lane >> 2, soff = (lane & 3) << 3;

  f32x4 acc[4][4] = {};

#pragma unroll
  for (int i = 0; i < 2; ++i) {
    const int c = 2 * wv + i;
    async_load16(A + (size_t)(m0 + 16 * c + srow) * K + soff, &A_lds[0][16 * c][0]);
    async_load16(Bt + (size_t)(n0 + 16 * c + srow) * K + soff, &B_lds[0][16 * c][0]);
  }

  int cur = 0;
  for (int t = 0; t < K / 32; ++t) {
    __syncthreads();
    if (t + 1 < K / 32) {
      const int k0 = (t + 1) << 5;
#pragma unroll
      for (int i = 0; i < 2; ++i) {
        const int c = 2 * wv + i;
        async_load16(A + (size_t)(m0 + 16 * c + srow) * K + k0 + soff,
                     &A_lds[cur ^ 1][16 * c][0]);
        async_load16(Bt + (size_t)(n0 + 16 * c + srow) * K + k0 + soff,
                     &B_lds[cur ^ 1][16 * c][0]);
      }
    }
    bf16x8 af[4], bfr[4];
#pragma unroll
    for (int i = 0; i < 4; ++i)
      af[i] = *(const bf16x8*)&A_lds[cur][64 * wr + 16 * i + l16][8 * lg];
#pragma unroll
    for (int j = 0; j < 4; ++j)
      bfr[j] = *(const bf16x8*)&B_lds[cur][64 * wc + 16 * j + l16][8 * lg];
#pragma unroll
    for (int i = 0; i < 4; ++i)
#pragma unroll
      for (int j = 0; j < 4; ++j)
        acc[i][j] = __builtin_amdgcn_mfma_f32_16x16x32_bf16(af[i], bfr[j], acc[i][j], 0, 0, 0);
    cur ^= 1;
  }

  const int mt = n0 >> 10;  // 0=Q 1=K 2=V (uniform per block)
  const float* bias = (mt == 0) ? bq : (mt == 1 ? bk : bv);
  const float qs = (mt == 0) ? 0.125f * 1.4426950408889634f : 1.0f;

  if (mt < 2) {
    short* Out = (mt == 0) ? Qo : Ko;
#pragma unroll
    for (int i = 0; i < 4; ++i) {
#pragma unroll
      for (int j = 0; j < 4; ++j) {
        const int nl = (n0 & 1023) + 64 * wc + 16 * j + l16;
        const float bvl = bias[nl];
        const int h = nl >> 6, d = nl & 63;
#pragma unroll
        for (int r = 0; r < 4; ++r) {
          const int m = m0 + 64 * wr + 16 * i + 4 * lg + r;
          const int b = m >> 11, s = m & (S_ - 1);
          Out[(((size_t)(b * NH_ + h) * S_ + s) << 6) + d] =
              f2bf((acc[i][j][r] + bvl) * qs);
        }
      }
    }
  } else {
#pragma unroll
    for (int i = 0; i < 4; ++i) {
      const int mb = m0 + 64 * wr + 16 * i + 4 * lg;
      const int b = mb >> 11, s = mb & (S_ - 1);
#pragma unroll
      for (int j = 0; j < 4; ++j) {
        const int nl = (n0 & 1023) + 64 * wc + 16 * j + l16;
        const float bvl = bias[nl];
        const int h = nl >> 6, d = nl & 63;
        bf16x4 pk;
#pragma unroll
        for (int r = 0; r < 4; ++r) pk[r] = f2bf(acc[i][j][r] + bvl);
        *(bf16x4*)&Vto[(((size_t)(b * NH_ + h) * HD_ + d) << 11) + s] = pk;
      }
    }
  }
}

// ---------------- O-projection GEMM: ctx_bf16 [M][1024] @ Wto^T -> fp32 ----------------
__global__ __launch_bounds__(256)
void gemm_o(const short* __restrict__ A, const short* __restrict__ Bt,
            const float* __restrict__ bias, float* __restrict__ C) {
  __shared__ short A_lds[2][128][32];
  __shared__ short B_lds[2][128][32];
  const int tid = threadIdx.x;
  const int lane = tid & 63, wv = tid >> 6;
  const int l16 = lane & 15, lg = lane >> 4;
  const int wr = wv >> 1, wc = wv & 1;
  const int swzb = (blockIdx.x & 7) * 32 + (blockIdx.x >> 3);
  const int bx = swzb & 7, by = swzb >> 3;
  const int m0 = by << 7, n0 = bx << 7;
  const int K = H_;

  const int srow = lane >> 2, soff = (lane & 3) << 3;

  f32x4 acc[4][4] = {};

#pragma unroll
  for (int i = 0; i < 2; ++i) {
    const int c = 2 * wv + i;
    async_load16(A + (size_t)(m0 + 16 * c + srow) * K + soff, &A_lds[0][16 * c][0]);
    async_load16(Bt + (size_t)(n0 + 16 * c + srow) * K + soff, &B_lds[0][16 * c][0]);
  }

  int cur = 0;
  for (int t = 0; t < K / 32; ++t) {
    __syncthreads();
    if (t + 1 < K / 32) {
      const int k0 = (t + 1) << 5;
#pragma unroll
      for (int i = 0; i < 2; ++i) {
        const int c = 2 * wv + i;
        async_load16(A + (size_t)(m0 + 16 * c + srow) * K + k0 + soff,
                     &A_lds[cur ^ 1][16 * c][0]);
        async_load16(Bt + (size_t)(n0 + 16 * c + srow) * K + k0 + soff,
                     &B_lds[cur ^ 1][16 * c][0]);
      }
    }
    bf16x8 af[4], bfr[4];
#pragma unroll
    for (int i = 0; i < 4; ++i)
      af[i] = *(const bf16x8*)&A_lds[cur][64 * wr + 16 * i + l16][8 * lg];
#pragma unroll
    for (int j = 0; j < 4; ++j)
      bfr[j] = *(const bf16x8*)&B_lds[cur][64 * wc + 16 * j + l16][8 * lg];
#pragma unroll
    for (int i = 0; i < 4; ++i)
#pragma unroll
      for (int j = 0; j < 4; ++j)
        acc[i][j] = __builtin_amdgcn_mfma_f32_16x16x32_bf16(af[i], bfr[j], acc[i][j], 0, 0, 0);
    cur ^= 1;
  }

#pragma unroll
  for (int i = 0; i < 4; ++i)
#pragma unroll
    for (int j = 0; j < 4; ++j) {
      const int n = n0 + 64 * wc + 16 * j + l16;
      const float bvl = bias[n];
#pragma unroll
      for (int r = 0; r < 4; ++r) {
        const int m = m0 + 64 * wr + 16 * i + 4 * lg + r;
        C[(size_t)m * H_ + n] = acc[i][j][r] + bvl;
      }
    }
}

// ---------------- Flash attention: swapped QK^T, in-register P ----------------
// Q,K bf16 [bh][s][64] (Q pre-scaled by 0.125*log2e); Vt bf16 [bh][d][S];
// ctx bf16 [B,S,NH,HD]. Scores in exp2 domain. Defer-max (T13, THR=8).
// Staging: reg-staged (T14 issue-early/write-late — round-5 schedule, 77.5us)
// with chunk-XOR swizzled ds_write slots + matching swizzled reads
// (round-8 pattern, 0 bank conflicts). LDS linear [64][64], 32 KB total.
#define KVB 64

__global__ __launch_bounds__(256)
void attn_mfma(const short* __restrict__ Qg, const short* __restrict__ Kg,
               const short* __restrict__ Vtg, short* __restrict__ ctxb) {
  __shared__ short K_lds[2][KVB][64];  // [kv][d], swizzled slots
  __shared__ short V_t[2][KVB][64];    // [d][kv], swizzled slots

  const int tid  = threadIdx.x;
  const int lane = tid & 63;
  const int wv   = tid >> 6;
  const int l16  = lane & 15, lg = lane >> 4;

  // XCD swizzle: 1024 blocks -> 128 consecutive per XCD
  const int swz = (blockIdx.x & 7) * 128 + (blockIdx.x >> 3);
  const int bh = swz >> 5, qb = swz & 31;

  const short* Qh = Qg + ((size_t)bh * S_ << 6);
  const short* Kh = Kg + ((size_t)bh * S_ << 6);
  const short* Vh = Vtg + ((size_t)bh << 6) * S_;  // [64][2048]

  const int q0 = qb * 64 + wv * 16;

  bf16x8 qf[2];
  qf[0] = *(const bf16x8*)&Qh[((size_t)(q0 + l16) << 6) + 8 * lg];
  qf[1] = *(const bf16x8*)&Qh[((size_t)(q0 + l16) << 6) + 8 * lg + 32];

  const int l16part = ((l16 >> 2) << 3) + (l16 & 3);  // K-row remap, lane part

  // staging mapping (256 threads cover 64 rows x 8 chunks):
  // row kr = tid>>2, logical chunks cb, cb+1 (cb = 2*(tid&3)); swizzled slots
  const int kr = tid >> 2;
  const int cb = (tid & 3) << 1;
  const int sz = swz8(kr);
  const int c1 = ((cb    ) ^ sz) << 3;  // short offset of swizzled slot
  const int c2 = ((cb + 1) ^ sz) << 3;

  f32x4 o[4] = {};
  float m_run = -1e30f, l_run = 0.f;  // stats for q-row l16 (replicated over lg)

  // prologue: stage tile 0 into buf 0 (direct, swizzled slots)
  {
    *(bf16x8*)&K_lds[0][kr][c1] = *(const bf16x8*)&Kh[((size_t)kr << 6) + (cb << 3)];
    *(bf16x8*)&K_lds[0][kr][c2] = *(const bf16x8*)&Kh[((size_t)kr << 6) + ((cb + 1) << 3)];
    *(bf16x8*)&V_t[0][kr][c1]   = *(const bf16x8*)&Vh[(size_t)kr * S_ + (cb << 3)];
    *(bf16x8*)&V_t[0][kr][c2]   = *(const bf16x8*)&Vh[(size_t)kr * S_ + ((cb + 1) << 3)];
  }

  int cur = 0;
  for (int t = 0; t < S_ / KVB; ++t) {
    // issue next-tile global loads early (latency hides under compute)
    bf16x8 nk0, nk1, nv0, nv1;
    const bool pre = (t + 1 < S_ / KVB);
    if (pre) {
      const size_t kb = (size_t)((t + 1) * KVB + kr) << 6;
      nk0 = *(const bf16x8*)&Kh[kb + (cb << 3)];
      nk1 = *(const bf16x8*)&Kh[kb + ((cb + 1) << 3)];
      const size_t vb = (size_t)kr * S_ + (t + 1) * KVB;
      nv0 = *(const bf16x8*)&Vh[vb + (cb << 3)];
      nv1 = *(const bf16x8*)&Vh[vb + ((cb + 1) << 3)];
    }
    __syncthreads();  // buf[cur] writes (from prev iter) visible

    // swapped QK^T with row-remap: s[tt] elem r holds
    // S2[kv = 32*(tt>>1) + 8*lg + 4*(tt&1) + r][q = l16]  (exp2 domain)
    f32x4 s[4] = {};
#pragma unroll
    for (int ks = 0; ks < 2; ++ks)
#pragma unroll
      for (int tt = 0; tt < 4; ++tt) {
        const int krow = ((tt >> 1) << 5) + ((tt & 1) << 2) + l16part;
        const int kch = (lg + 4 * ks) ^ swz8(krow);
        bf16x8 kf = *(const bf16x8*)&K_lds[cur][krow][kch << 3];
        s[tt] = __builtin_amdgcn_mfma_f32_16x16x32_bf16(kf, qf[ks], s[tt], 0, 0, 0);
      }

    // tile max for q=l16: in-lane 16 + xor over lanes 16,32
    float pmax = fmaxf(fmaxf(fmaxf(s[0][0], s[0][1]), fmaxf(s[0][2], s[0][3])),
                       fmaxf(fmaxf(s[1][0], s[1][1]), fmaxf(s[1][2], s[1][3])));
    pmax = fmaxf(pmax,
                 fmaxf(fmaxf(fmaxf(s[2][0], s[2][1]), fmaxf(s[2][2], s[2][3])),
                       fmaxf(fmaxf(s[3][0], s[3][1]), fmaxf(s[3][2], s[3][3]))));
    pmax = fmaxf(pmax, __shfl_xor(pmax, 16));
    pmax = fmaxf(pmax, __shfl_xor(pmax, 32));

    float p[4][4];
    float rs = 0.f;
    if (__any(pmax - m_run > 8.0f)) {   // rescale path (rare after warmup)
      const float mn = fmaxf(m_run, pmax);
      const float scl = __builtin_amdgcn_exp2f(m_run - mn);
      m_run = mn;
#pragma unroll
      for (int tt = 0; tt < 4; ++tt)
#pragma unroll
        for (int r = 0; r < 4; ++r) {
          p[tt][r] = __builtin_amdgcn_exp2f(s[tt][r] - mn);
          rs += p[tt][r];
        }
      rs += __shfl_xor(rs, 16);
      rs += __shfl_xor(rs, 32);
      l_run = l_run * scl + rs;
      float sclr[4];
#pragma unroll
      for (int r = 0; r < 4; ++r) sclr[r] = __shfl(scl, 4 * lg + r);
#pragma unroll
      for (int tt = 0; tt < 4; ++tt)
#pragma unroll
        for (int r = 0; r < 4; ++r) o[tt][r] *= sclr[r];
    } else {                            // defer path: P <= 2^8, no o-rescale
#pragma unroll
      for (int tt = 0; tt < 4; ++tt)
#pragma unroll
        for (int r = 0; r < 4; ++r) {
          p[tt][r] = __builtin_amdgcn_exp2f(s[tt][r] - m_run);
          rs += p[tt][r];
        }
      rs += __shfl_xor(rs, 16);
      rs += __shfl_xor(rs, 32);
      l_run += rs;
    }

    // pack P to bf16 (lane-local PV A-fragments)
    unsigned w[4][2];
#pragma unroll
    for (int tt = 0; tt < 4; ++tt) {
      w[tt][0] = cvt_pk_bf16(p[tt][0], p[tt][1]);
      w[tt][1] = cvt_pk_bf16(p[tt][2], p[tt][3]);
    }

    // PV: A = P (in-register), B = V^T rows (swizzled b128 reads)
#pragma unroll
    for (int ks = 0; ks < 2; ++ks) {
      i32x4 aw;
      aw[0] = (int)w[2 * ks][0];
      aw[1] = (int)w[2 * ks][1];
      aw[2] = (int)w[2 * ks + 1][0];
      aw[3] = (int)w[2 * ks + 1][1];
      const bf16x8 pf = __builtin_bit_cast(bf16x8, aw);
#pragma unroll
      for (int tt = 0; tt < 4; ++tt) {
        const int vrow = 16 * tt + l16;
        const int vch = (lg + 4 * ks) ^ swz8(vrow);
        bf16x8 vf = *(const bf16x8*)&V_t[cur][vrow][vch << 3];
        o[tt] = __builtin_amdgcn_mfma_f32_16x16x32_bf16(pf, vf, o[tt], 0, 0, 0);
      }
    }

    // write next tile into buf[cur^1] (T14 write-late; other waves still
    // read buf[cur] — different buffer, next barrier publishes)
    if (pre) {
      *(bf16x8*)&K_lds[cur ^ 1][kr][c1] = nk0;
      *(bf16x8*)&K_lds[cur ^ 1][kr][c2] = nk1;
      *(bf16x8*)&V_t[cur ^ 1][kr][c1]   = nv0;
      *(bf16x8*)&V_t[cur ^ 1][kr][c2]   = nv1;
    }
    cur ^= 1;
  }

  // epilogue: ctx[b][s][h*64+d] bf16; rows q = 4lg+r, cols d = 16tt+l16
  float invr[4];
#pragma unroll
  for (int r = 0; r < 4; ++r) invr[r] = 1.f / __shfl(l_run, 4 * lg + r);
  const int b = bh >> 4, h = bh & 15;
#pragma unroll
  for (int r = 0; r < 4; ++r) {
    const int q = q0 + 4 * lg + r;
#pragma unroll
    for (int tt = 0; tt < 4; ++tt)
      ctxb[(((size_t)(b * S_ + q) * NH_ + h) << 6) + 16 * tt + l16] =
          f2bf(o[tt][r] * invr[r]);
  }
}

// ---------------- residual + LayerNorm ----------------
__global__ __launch_bounds__(256)
void resid_ln(const float* __restrict__ attn_out, const float* __restrict__ hs,
              const float* __restrict__ gamma, const float* __restrict__ beta,
              float* __restrict__ out) {
  __shared__ float reds[4], reds2[4];
  const int row = blockIdx.x;
  const int tid = threadIdx.x;
  const float4* a4 = (const float4*)(attn_out + ((size_t)row << 10));
  const float4* h4 = (const float4*)(hs + ((size_t)row << 10));
  float4 a = a4[tid], h = h4[tid];
  float e0 = a.x + h.x, e1 = a.y + h.y, e2 = a.z + h.z, e3 = a.w + h.w;
  float s  = e0 + e1 + e2 + e3;
  float sq = e0 * e0 + e1 * e1 + e2 * e2 + e3 * e3;
  s = waveReduceSum(s);
  sq = waveReduceSum(sq);
  const int lane = tid & 63, wave = tid >> 6;
  if (lane == 0) { reds[wave] = s; reds2[wave] = sq; }
  __syncthreads();
  const float S1 = reds[0] + reds[1] + reds[2] + reds[3];
  const float S2 = reds2[0] + reds2[1] + reds2[2] + reds2[3];
  const float mu = S1 * (1.f / H_);
  const float var = S2 * (1.f / H_) - mu * mu;
  const float rstd = rsqrtf(var + 1e-12f);
  const float4 g = ((const float4*)gamma)[tid];
  const float4 bb = ((const float4*)beta)[tid];
  float4 o;
  o.x = (e0 - mu) * rstd * g.x + bb.x;
  o.y = (e1 - mu) * rstd * g.y + bb.y;
  o.z = (e2 - mu) * rstd * g.z + bb.z;
  o.w = (e3 - mu) * rstd * g.w + bb.w;
  ((float4*)(out + ((size_t)row << 10)))[tid] = o;
}

extern "C" void kernel_launch(void* const* d_in, const int* in_sizes, int n_in,
                              void* d_out, int out_size, void* d_ws, size_t ws_size,
                              hipStream_t stream) {
  const float* X     = (const float*)d_in[0];
  const float* Wq    = (const float*)d_in[1];
  const float* bq    = (const float*)d_in[2];
  const float* Wk    = (const float*)d_in[3];
  const float* bk    = (const float*)d_in[4];
  const float* Wv    = (const float*)d_in[5];
  const float* bv    = (const float*)d_in[6];
  const float* Wo    = (const float*)d_in[7];
  const float* bo    = (const float*)d_in[8];
  const float* gamma = (const float*)d_in[9];
  const float* beta  = (const float*)d_in[10];
  float* out = (float*)d_out;

  // workspace layout (peak 40 MB)
  char* ws = (char*)d_ws;
  short* Xbf  = (short*)ws;                        // 8 MB [M][H] bf16
  short* Wqkv = (short*)(ws + ( 8u << 20));        // 6 MB [3072][1024] bf16
  short* Wto  = (short*)(ws + (14u << 20));        // 2 MB [1024][1024] bf16
  short* Qbf  = (short*)(ws + (16u << 20));        // 8 MB [bh][s][64] (pre-scaled)
  short* Kbf  = (short*)(ws + (24u << 20));        // 8 MB [bh][s][64]
  short* Vt   = (short*)(ws + (32u << 20));        // 8 MB [bh][d][S] (transposed)
  short* ctxb = Xbf;                               // ctx bf16 overwrites Xbf (dead)
  float* attn = (float*)(ws + (16u << 20));        // fp32, overwrites Q/K (dead)

  dim3 blk(256);
  hipLaunchKernelGGL(cvt_bf16, dim3((M_ * H_) / 1024), blk, 0, stream, X, Xbf);
  hipLaunchKernelGGL(transpose_w4, dim3(32, 32, 4), blk, 0, stream,
                     Wq, Wk, Wv, Wo, Wqkv, Wto);
  hipLaunchKernelGGL(gemm_qkv, dim3(768), blk, 0, stream,
                     Xbf, Wqkv, bq, bk, bv, Qbf, Kbf, Vt);
  hipLaunchKernelGGL(attn_mfma, dim3(1024), blk, 0, stream, Qbf, Kbf, Vt, ctxb);
  hipLaunchKernelGGL(gemm_o, dim3(256), blk, 0, stream, ctxb, Wto, bo, attn);
  hipLaunchKernelGGL(resid_ln, dim3(M_), blk, 0, stream, attn, X, gamma, beta, out);
}

// Round 11
// 244.412 us; speedup vs baseline: 1.1026x; 1.0492x over previous
//
#include <hip/hip_runtime.h>
#include <hip/hip_bf16.h>

#define B_ 2
#define S_ 2048
#define H_ 1024
#define NH_ 16
#define HD_ 64
#define M_ (B_*S_)   // 4096 rows

typedef __attribute__((ext_vector_type(8))) short bf16x8;
typedef __attribute__((ext_vector_type(4))) short bf16x4;
typedef __attribute__((ext_vector_type(4))) float f32x4;
typedef __attribute__((ext_vector_type(4))) int   i32x4;

// ---------------- helpers ----------------
__device__ inline float waveReduceSum(float v) {
#pragma unroll
  for (int off = 32; off >= 1; off >>= 1) v += __shfl_xor(v, off);
  return v;
}

__device__ inline short f2bf(float f) {
  union { float f; unsigned u; } v; v.f = f;
  unsigned r = v.u + 0x7fffu + ((v.u >> 16) & 1u);  // RNE
  return (short)(r >> 16);
}

__device__ inline unsigned cvt_pk_bf16(float lo, float hi) {
  unsigned w;
  asm("v_cvt_pk_bf16_f32 %0, %1, %2" : "=v"(w) : "v"(lo), "v"(hi));
  return w;
}

__device__ inline void async_load16(const void* g, void* l) {
  __builtin_amdgcn_global_load_lds(
      (const __attribute__((address_space(1))) void*)g,
      (__attribute__((address_space(3))) void*)l, 16, 0, 0);
}

// 16B-chunk swizzle within a 128B LDS row (8 chunks); row in [0,64)
__device__ inline int swz8(int r) { return (r & 3) | (((r >> 3) & 1) << 2); }

// ---------------- fp32 -> bf16 convert (X) ----------------
__global__ __launch_bounds__(256)
void cvt_bf16(const float* __restrict__ in, short* __restrict__ out) {
  const size_t i = (size_t)blockIdx.x * 256 + threadIdx.x;
  float4 v = ((const float4*)in)[i];
  bf16x4 o;
  o[0] = f2bf(v.x); o[1] = f2bf(v.y); o[2] = f2bf(v.z); o[3] = f2bf(v.w);
  ((bf16x4*)out)[i] = o;
}

// ---------------- W[k][n] fp32 -> Wt[n][k] bf16 (QKV packed + O) ----------------
__global__ __launch_bounds__(256)
void transpose_w4(const float* __restrict__ W0, const float* __restrict__ W1,
                  const float* __restrict__ W2, const float* __restrict__ W3,
                  short* __restrict__ Tqkv, short* __restrict__ To) {
  const float* W; short* T;
  switch (blockIdx.z) {
    case 0: W = W0; T = Tqkv; break;
    case 1: W = W1; T = Tqkv + (size_t)1024 * 1024; break;
    case 2: W = W2; T = Tqkv + (size_t)2048 * 1024; break;
    default: W = W3; T = To; break;
  }
  __shared__ float tile[32][36];
  const int tid = threadIdx.x;
  const int tx = tid & 7, ty = tid >> 3;
  const int k0 = blockIdx.y << 5, n0 = blockIdx.x << 5;
  float4 v = *(const float4*)&W[(size_t)(k0 + ty) * H_ + n0 + (tx << 2)];
  tile[ty][(tx << 2) + 0] = v.x;
  tile[ty][(tx << 2) + 1] = v.y;
  tile[ty][(tx << 2) + 2] = v.z;
  tile[ty][(tx << 2) + 3] = v.w;
  __syncthreads();
  bf16x4 o;
  o[0] = f2bf(tile[(tx << 2) + 0][ty]);
  o[1] = f2bf(tile[(tx << 2) + 1][ty]);
  o[2] = f2bf(tile[(tx << 2) + 2][ty]);
  o[3] = f2bf(tile[(tx << 2) + 3][ty]);
  *(bf16x4*)&T[(size_t)(n0 + ty) * H_ + k0 + (tx << 2)] = o;
}

// ---------------- fused QKV GEMM: [4096,1024] @ [1024,3072] ----------------
// Q (n<1024): bf16 head layout, pre-scaled by 0.125*log2(e)  (exp2-domain scores)
// K: bf16 head layout. V: bf16 transposed [bh][d][S].
__global__ __launch_bounds__(256)
void gemm_qkv(const short* __restrict__ A, const short* __restrict__ Bt,
              const float* __restrict__ bq, const float* __restrict__ bk,
              const float* __restrict__ bv, short* __restrict__ Qo,
              short* __restrict__ Ko, short* __restrict__ Vto) {
  __shared__ short A_lds[2][128][32];
  __shared__ short B_lds[2][128][32];
  const int tid = threadIdx.x;
  const int lane = tid & 63, wv = tid >> 6;
  const int l16 = lane & 15, lg = lane >> 4;
  const int wr = wv >> 1, wc = wv & 1;
  const int swzb = (blockIdx.x & 7) * 96 + (blockIdx.x >> 3);
  const int bx = swzb % 24, by = swzb / 24;
  const int m0 = by << 7, n0 = bx << 7;
  const int K = H_;

  const int srow = lane >> 2, soff = (lane & 3) << 3;

  f32x4 acc[4][4] = {};

#pragma unroll
  for (int i = 0; i < 2; ++i) {
    const int c = 2 * wv + i;
    async_load16(A + (size_t)(m0 + 16 * c + srow) * K + soff, &A_lds[0][16 * c][0]);
    async_load16(Bt + (size_t)(n0 + 16 * c + srow) * K + soff, &B_lds[0][16 * c][0]);
  }

  int cur = 0;
  for (int t = 0; t < K / 32; ++t) {
    __syncthreads();
    if (t + 1 < K / 32) {
      const int k0 = (t + 1) << 5;
#pragma unroll
      for (int i = 0; i < 2; ++i) {
        const int c = 2 * wv + i;
        async_load16(A + (size_t)(m0 + 16 * c + srow) * K + k0 + soff,
                     &A_lds[cur ^ 1][16 * c][0]);
        async_load16(Bt + (size_t)(n0 + 16 * c + srow) * K + k0 + soff,
                     &B_lds[cur ^ 1][16 * c][0]);
      }
    }
    bf16x8 af[4], bfr[4];
#pragma unroll
    for (int i = 0; i < 4; ++i)
      af[i] = *(const bf16x8*)&A_lds[cur][64 * wr + 16 * i + l16][8 * lg];
#pragma unroll
    for (int j = 0; j < 4; ++j)
      bfr[j] = *(const bf16x8*)&B_lds[cur][64 * wc + 16 * j + l16][8 * lg];
#pragma unroll
    for (int i = 0; i < 4; ++i)
#pragma unroll
      for (int j = 0; j < 4; ++j)
        acc[i][j] = __builtin_amdgcn_mfma_f32_16x16x32_bf16(af[i], bfr[j], acc[i][j], 0, 0, 0);
    cur ^= 1;
  }

  const int mt = n0 >> 10;  // 0=Q 1=K 2=V (uniform per block)
  const float* bias = (mt == 0) ? bq : (mt == 1 ? bk : bv);
  const float qs = (mt == 0) ? 0.125f * 1.4426950408889634f : 1.0f;

  if (mt < 2) {
    short* Out = (mt == 0) ? Qo : Ko;
#pragma unroll
    for (int i = 0; i < 4; ++i) {
#pragma unroll
      for (int j = 0; j < 4; ++j) {
        const int nl = (n0 & 1023) + 64 * wc + 16 * j + l16;
        const float bvl = bias[nl];
        const int h = nl >> 6, d = nl & 63;
#pragma unroll
        for (int r = 0; r < 4; ++r) {
          const int m = m0 + 64 * wr + 16 * i + 4 * lg + r;
          const int b = m >> 11, s = m & (S_ - 1);
          Out[(((size_t)(b * NH_ + h) * S_ + s) << 6) + d] =
              f2bf((acc[i][j][r] + bvl) * qs);
        }
      }
    }
  } else {
#pragma unroll
    for (int i = 0; i < 4; ++i) {
      const int mb = m0 + 64 * wr + 16 * i + 4 * lg;
      const int b = mb >> 11, s = mb & (S_ - 1);
#pragma unroll
      for (int j = 0; j < 4; ++j) {
        const int nl = (n0 & 1023) + 64 * wc + 16 * j + l16;
        const float bvl = bias[nl];
        const int h = nl >> 6, d = nl & 63;
        bf16x4 pk;
#pragma unroll
        for (int r = 0; r < 4; ++r) pk[r] = f2bf(acc[i][j][r] + bvl);
        *(bf16x4*)&Vto[(((size_t)(b * NH_ + h) * HD_ + d) << 11) + s] = pk;
      }
    }
  }
}

// ---------------- O-projection GEMM: 64x128 tiles (512 blocks = 2/CU) ----------------
__global__ __launch_bounds__(256)
void gemm_o(const short* __restrict__ A, const short* __restrict__ Bt,
            const float* __restrict__ bias, float* __restrict__ C) {
  __shared__ short A_lds[2][64][32];   // 4 KB per buf
  __shared__ short B_lds[2][128][32];  // 8 KB per buf
  const int tid = threadIdx.x;
  const int lane = tid & 63, wv = tid >> 6;
  const int l16 = lane & 15, lg = lane >> 4;
  const int wr = wv >> 1, wc = wv & 1;
  const int swzb = (blockIdx.x & 7) * 64 + (blockIdx.x >> 3);  // 512 blocks bijective
  const int bx = swzb & 7, by = swzb >> 3;
  const int m0 = by << 6, n0 = bx << 7;
  const int K = H_;

  const int srow = lane >> 2, soff = (lane & 3) << 3;

  f32x4 acc[2][4] = {};

  // prologue: A (64 rows): 1 load/wave; B (128 rows): 2 loads/wave
  async_load16(A + (size_t)(m0 + 16 * wv + srow) * K + soff, &A_lds[0][16 * wv][0]);
#pragma unroll
  for (int i = 0; i < 2; ++i) {
    const int c = 2 * wv + i;
    async_load16(Bt + (size_t)(n0 + 16 * c + srow) * K + soff, &B_lds[0][16 * c][0]);
  }

  int cur = 0;
  for (int t = 0; t < K / 32; ++t) {
    __syncthreads();
    if (t + 1 < K / 32) {
      const int k0 = (t + 1) << 5;
      async_load16(A + (size_t)(m0 + 16 * wv + srow) * K + k0 + soff,
                   &A_lds[cur ^ 1][16 * wv][0]);
#pragma unroll
      for (int i = 0; i < 2; ++i) {
        const int c = 2 * wv + i;
        async_load16(Bt + (size_t)(n0 + 16 * c + srow) * K + k0 + soff,
                     &B_lds[cur ^ 1][16 * c][0]);
      }
    }
    bf16x8 af[2], bfr[4];
#pragma unroll
    for (int i = 0; i < 2; ++i)
      af[i] = *(const bf16x8*)&A_lds[cur][32 * wr + 16 * i + l16][8 * lg];
#pragma unroll
    for (int j = 0; j < 4; ++j)
      bfr[j] = *(const bf16x8*)&B_lds[cur][64 * wc + 16 * j + l16][8 * lg];
#pragma unroll
    for (int i = 0; i < 2; ++i)
#pragma unroll
      for (int j = 0; j < 4; ++j)
        acc[i][j] = __builtin_amdgcn_mfma_f32_16x16x32_bf16(af[i], bfr[j], acc[i][j], 0, 0, 0);
    cur ^= 1;
  }

#pragma unroll
  for (int i = 0; i < 2; ++i)
#pragma unroll
    for (int j = 0; j < 4; ++j) {
      const int n = n0 + 64 * wc + 16 * j + l16;
      const float bvl = bias[n];
#pragma unroll
      for (int r = 0; r < 4; ++r) {
        const int m = m0 + 32 * wr + 16 * i + 4 * lg + r;
        C[(size_t)m * H_ + n] = acc[i][j][r] + bvl;
      }
    }
}

// ---------------- Flash attention: swapped QK^T, in-register P ----------------
// Q,K bf16 [bh][s][64] (Q pre-scaled by 0.125*log2e); Vt bf16 [bh][d][S];
// ctx bf16 [B,S,NH,HD]. exp2-domain scores, defer-max (T13, THR=8).
// KV tile = 128, as 2 subtiles of 64 reusing the verified swizzle algebra.
// Reg-staged (T14) + chunk-XOR swizzled slots (0 conflicts). LDS 64 KB.
// setprio(1) around MFMA clusters (T5 — independent blocks, m191 regime).
__global__ __launch_bounds__(256)
void attn_mfma(const short* __restrict__ Qg, const short* __restrict__ Kg,
               const short* __restrict__ Vtg, short* __restrict__ ctxb) {
  __shared__ short K_lds[2][2][64][64];  // [buf][half][kv][d], swizzled slots
  __shared__ short V_t[2][2][64][64];    // [buf][half][d][kv], swizzled slots

  const int tid  = threadIdx.x;
  const int lane = tid & 63;
  const int wv   = tid >> 6;
  const int l16  = lane & 15, lg = lane >> 4;

  // XCD swizzle: 1024 blocks -> 128 consecutive per XCD
  const int swz = (blockIdx.x & 7) * 128 + (blockIdx.x >> 3);
  const int bh = swz >> 5, qb = swz & 31;

  const short* Qh = Qg + ((size_t)bh * S_ << 6);
  const short* Kh = Kg + ((size_t)bh * S_ << 6);
  const short* Vh = Vtg + ((size_t)bh << 6) * S_;  // [64][2048]

  const int q0 = qb * 64 + wv * 16;

  bf16x8 qf[2];
  qf[0] = *(const bf16x8*)&Qh[((size_t)(q0 + l16) << 6) + 8 * lg];
  qf[1] = *(const bf16x8*)&Qh[((size_t)(q0 + l16) << 6) + 8 * lg + 32];

  const int l16part = ((l16 >> 2) << 3) + (l16 & 3);  // K-row remap, lane part

  // staging mapping per half (256 threads cover 64 rows x 8 chunks):
  const int kr = tid >> 2;
  const int cb = (tid & 3) << 1;
  const int sz = swz8(kr);
  const int c1 = ((cb    ) ^ sz) << 3;
  const int c2 = ((cb + 1) ^ sz) << 3;

  f32x4 o[4] = {};
  float m_run = -1e30f, l_run = 0.f;  // stats for q-row l16 (replicated over lg)

  // prologue: stage tile 0 (both halves) into buf 0
#pragma unroll
  for (int h = 0; h < 2; ++h) {
    const size_t kg = ((size_t)(64 * h + kr)) << 6;
    *(bf16x8*)&K_lds[0][h][kr][c1] = *(const bf16x8*)&Kh[kg + (cb << 3)];
    *(bf16x8*)&K_lds[0][h][kr][c2] = *(const bf16x8*)&Kh[kg + ((cb + 1) << 3)];
    const size_t vg = (size_t)kr * S_ + 64 * h;
    *(bf16x8*)&V_t[0][h][kr][c1]   = *(const bf16x8*)&Vh[vg + (cb << 3)];
    *(bf16x8*)&V_t[0][h][kr][c2]   = *(const bf16x8*)&Vh[vg + ((cb + 1) << 3)];
  }

  int cur = 0;
  for (int t = 0; t < S_ / 128; ++t) {
    // issue next-tile global loads early (latency hides under compute)
    bf16x8 nk[2][2], nv[2][2];
    const bool pre = (t + 1 < S_ / 128);
    if (pre) {
      const int kvn = (t + 1) * 128;
#pragma unroll
      for (int h = 0; h < 2; ++h) {
        const size_t kb = ((size_t)(kvn + 64 * h + kr)) << 6;
        nk[h][0] = *(const bf16x8*)&Kh[kb + (cb << 3)];
        nk[h][1] = *(const bf16x8*)&Kh[kb + ((cb + 1) << 3)];
        const size_t vb = (size_t)kr * S_ + kvn + 64 * h;
        nv[h][0] = *(const bf16x8*)&Vh[vb + (cb << 3)];
        nv[h][1] = *(const bf16x8*)&Vh[vb + ((cb + 1) << 3)];
      }
    }
    __syncthreads();  // buf[cur] writes (from prev iter) visible

    // swapped QK^T with row-remap: s[h][tt] elem r holds
    // S2[kv = 128t + 64h + 32*(tt>>1) + 8*lg + 4*(tt&1) + r][q = l16]
    f32x4 s[2][4] = {};
    __builtin_amdgcn_s_setprio(1);
#pragma unroll
    for (int h = 0; h < 2; ++h)
#pragma unroll
      for (int ks = 0; ks < 2; ++ks)
#pragma unroll
        for (int tt = 0; tt < 4; ++tt) {
          const int krow = ((tt >> 1) << 5) + ((tt & 1) << 2) + l16part;
          const int kch = (lg + 4 * ks) ^ swz8(krow);
          bf16x8 kf = *(const bf16x8*)&K_lds[cur][h][krow][kch << 3];
          s[h][tt] = __builtin_amdgcn_mfma_f32_16x16x32_bf16(kf, qf[ks], s[h][tt], 0, 0, 0);
        }
    __builtin_amdgcn_s_setprio(0);

    // tile max for q=l16: in-lane 32 + xor over lanes 16,32
    float pmax = -1e30f;
#pragma unroll
    for (int h = 0; h < 2; ++h)
#pragma unroll
      for (int tt = 0; tt < 4; ++tt)
        pmax = fmaxf(pmax, fmaxf(fmaxf(s[h][tt][0], s[h][tt][1]),
                                 fmaxf(s[h][tt][2], s[h][tt][3])));
    pmax = fmaxf(pmax, __shfl_xor(pmax, 16));
    pmax = fmaxf(pmax, __shfl_xor(pmax, 32));

    float p[2][4][4];
    float rs = 0.f;
    if (__any(pmax - m_run > 8.0f)) {   // rescale path (rare after warmup)
      const float mn = fmaxf(m_run, pmax);
      const float scl = __builtin_amdgcn_exp2f(m_run - mn);
      m_run = mn;
#pragma unroll
      for (int h = 0; h < 2; ++h)
#pragma unroll
        for (int tt = 0; tt < 4; ++tt)
#pragma unroll
          for (int r = 0; r < 4; ++r) {
            p[h][tt][r] = __builtin_amdgcn_exp2f(s[h][tt][r] - mn);
            rs += p[h][tt][r];
          }
      rs += __shfl_xor(rs, 16);
      rs += __shfl_xor(rs, 32);
      l_run = l_run * scl + rs;
      float sclr[4];
#pragma unroll
      for (int r = 0; r < 4; ++r) sclr[r] = __shfl(scl, 4 * lg + r);
#pragma unroll
      for (int tt = 0; tt < 4; ++tt)
#pragma unroll
        for (int r = 0; r < 4; ++r) o[tt][r] *= sclr[r];
    } else {                            // defer path: P <= 2^8, no o-rescale
#pragma unroll
      for (int h = 0; h < 2; ++h)
#pragma unroll
        for (int tt = 0; tt < 4; ++tt)
#pragma unroll
          for (int r = 0; r < 4; ++r) {
            p[h][tt][r] = __builtin_amdgcn_exp2f(s[h][tt][r] - m_run);
            rs += p[h][tt][r];
          }
      rs += __shfl_xor(rs, 16);
      rs += __shfl_xor(rs, 32);
      l_run += rs;
    }

    // pack P to bf16 (lane-local PV A-fragments)
    unsigned w[2][4][2];
#pragma unroll
    for (int h = 0; h < 2; ++h)
#pragma unroll
      for (int tt = 0; tt < 4; ++tt) {
        w[h][tt][0] = cvt_pk_bf16(p[h][tt][0], p[h][tt][1]);
        w[h][tt][1] = cvt_pk_bf16(p[h][tt][2], p[h][tt][3]);
      }

    // PV: A = P (in-register), B = V^T rows (swizzled b128 reads)
    __builtin_amdgcn_s_setprio(1);
#pragma unroll
    for (int h = 0; h < 2; ++h)
#pragma unroll
      for (int ks = 0; ks < 2; ++ks) {
        i32x4 aw;
        aw[0] = (int)w[h][2 * ks][0];
        aw[1] = (int)w[h][2 * ks][1];
        aw[2] = (int)w[h][2 * ks + 1][0];
        aw[3] = (int)w[h][2 * ks + 1][1];
        const bf16x8 pf = __builtin_bit_cast(bf16x8, aw);
#pragma unroll
        for (int tt = 0; tt < 4; ++tt) {
          const int vrow = 16 * tt + l16;
          const int vch = (lg + 4 * ks) ^ swz8(vrow);
          bf16x8 vf = *(const bf16x8*)&V_t[cur][h][vrow][vch << 3];
          o[tt] = __builtin_amdgcn_mfma_f32_16x16x32_bf16(pf, vf, o[tt], 0, 0, 0);
        }
      }
    __builtin_amdgcn_s_setprio(0);

    // write next tile into buf[cur^1] (T14 write-late)
    if (pre) {
#pragma unroll
      for (int h = 0; h < 2; ++h) {
        *(bf16x8*)&K_lds[cur ^ 1][h][kr][c1] = nk[h][0];
        *(bf16x8*)&K_lds[cur ^ 1][h][kr][c2] = nk[h][1];
        *(bf16x8*)&V_t[cur ^ 1][h][kr][c1]   = nv[h][0];
        *(bf16x8*)&V_t[cur ^ 1][h][kr][c2]   = nv[h][1];
      }
    }
    cur ^= 1;
  }

  // epilogue: ctx[b][s][h*64+d] bf16; rows q = 4lg+r, cols d = 16tt+l16
  float invr[4];
#pragma unroll
  for (int r = 0; r < 4; ++r) invr[r] = 1.f / __shfl(l_run, 4 * lg + r);
  const int b = bh >> 4, h = bh & 15;
#pragma unroll
  for (int r = 0; r < 4; ++r) {
    const int q = q0 + 4 * lg + r;
#pragma unroll
    for (int tt = 0; tt < 4; ++tt)
      ctxb[(((size_t)(b * S_ + q) * NH_ + h) << 6) + 16 * tt + l16] =
          f2bf(o[tt][r] * invr[r]);
  }
}

// ---------------- residual + LayerNorm ----------------
__global__ __launch_bounds__(256)
void resid_ln(const float* __restrict__ attn_out, const float* __restrict__ hs,
              const float* __restrict__ gamma, const float* __restrict__ beta,
              float* __restrict__ out) {
  __shared__ float reds[4], reds2[4];
  const int row = blockIdx.x;
  const int tid = threadIdx.x;
  const float4* a4 = (const float4*)(attn_out + ((size_t)row << 10));
  const float4* h4 = (const float4*)(hs + ((size_t)row << 10));
  float4 a = a4[tid], h = h4[tid];
  float e0 = a.x + h.x, e1 = a.y + h.y, e2 = a.z + h.z, e3 = a.w + h.w;
  float s  = e0 + e1 + e2 + e3;
  float sq = e0 * e0 + e1 * e1 + e2 * e2 + e3 * e3;
  s = waveReduceSum(s);
  sq = waveReduceSum(sq);
  const int lane = tid & 63, wave = tid >> 6;
  if (lane == 0) { reds[wave] = s; reds2[wave] = sq; }
  __syncthreads();
  const float S1 = reds[0] + reds[1] + reds[2] + reds[3];
  const float S2 = reds2[0] + reds2[1] + reds2[2] + reds2[3];
  const float mu = S1 * (1.f / H_);
  const float var = S2 * (1.f / H_) - mu * mu;
  const float rstd = rsqrtf(var + 1e-12f);
  const float4 g = ((const float4*)gamma)[tid];
  const float4 bb = ((const float4*)beta)[tid];
  float4 o;
  o.x = (e0 - mu) * rstd * g.x + bb.x;
  o.y = (e1 - mu) * rstd * g.y + bb.y;
  o.z = (e2 - mu) * rstd * g.z + bb.z;
  o.w = (e3 - mu) * rstd * g.w + bb.w;
  ((float4*)(out + ((size_t)row << 10)))[tid] = o;
}

extern "C" void kernel_launch(void* const* d_in, const int* in_sizes, int n_in,
                              void* d_out, int out_size, void* d_ws, size_t ws_size,
                              hipStream_t stream) {
  const float* X     = (const float*)d_in[0];
  const float* Wq    = (const float*)d_in[1];
  const float* bq    = (const float*)d_in[2];
  const float* Wk    = (const float*)d_in[3];
  const float* bk    = (const float*)d_in[4];
  const float* Wv    = (const float*)d_in[5];
  const float* bv    = (const float*)d_in[6];
  const float* Wo    = (const float*)d_in[7];
  const float* bo    = (const float*)d_in[8];
  const float* gamma = (const float*)d_in[9];
  const float* beta  = (const float*)d_in[10];
  float* out = (float*)d_out;

  // workspace layout (peak 40 MB)
  char* ws = (char*)d_ws;
  short* Xbf  = (short*)ws;                        // 8 MB [M][H] bf16
  short* Wqkv = (short*)(ws + ( 8u << 20));        // 6 MB [3072][1024] bf16
  short* Wto  = (short*)(ws + (14u << 20));        // 2 MB [1024][1024] bf16
  short* Qbf  = (short*)(ws + (16u << 20));        // 8 MB [bh][s][64] (pre-scaled)
  short* Kbf  = (short*)(ws + (24u << 20));        // 8 MB [bh][s][64]
  short* Vt   = (short*)(ws + (32u << 20));        // 8 MB [bh][d][S] (transposed)
  short* ctxb = Xbf;                               // ctx bf16 overwrites Xbf (dead)
  float* attn = (float*)(ws + (16u << 20));        // fp32, overwrites Q/K (dead)

  dim3 blk(256);
  hipLaunchKernelGGL(cvt_bf16, dim3((M_ * H_) / 1024), blk, 0, stream, X, Xbf);
  hipLaunchKernelGGL(transpose_w4, dim3(32, 32, 4), blk, 0, stream,
                     Wq, Wk, Wv, Wo, Wqkv, Wto);
  hipLaunchKernelGGL(gemm_qkv, dim3(768), blk, 0, stream,
                     Xbf, Wqkv, bq, bk, bv, Qbf, Kbf, Vt);
  hipLaunchKernelGGL(attn_mfma, dim3(1024), blk, 0, stream, Qbf, Kbf, Vt, ctxb);
  hipLaunchKernelGGL(gemm_o, dim3(512), blk, 0, stream, ctxb, Wto, bo, attn);
  hipLaunchKernelGGL(resid_ln, dim3(M_), blk, 0, stream, attn, X, gamma, beta, out);
}

// Round 13
// 237.690 us; speedup vs baseline: 1.1338x; 1.0283x over previous
//
#include <hip/hip_runtime.h>
#include <hip/hip_bf16.h>

#define B_ 2
#define S_ 2048
#define H_ 1024
#define NH_ 16
#define HD_ 64
#define M_ (B_*S_)   // 4096 rows

typedef __attribute__((ext_vector_type(8))) short bf16x8;
typedef __attribute__((ext_vector_type(4))) short bf16x4;
typedef __attribute__((ext_vector_type(4))) float f32x4;
typedef __attribute__((ext_vector_type(4))) int   i32x4;

// ---------------- helpers ----------------
__device__ inline float waveReduceSum(float v) {
#pragma unroll
  for (int off = 32; off >= 1; off >>= 1) v += __shfl_xor(v, off);
  return v;
}

__device__ inline short f2bf(float f) {
  union { float f; unsigned u; } v; v.f = f;
  unsigned r = v.u + 0x7fffu + ((v.u >> 16) & 1u);  // RNE
  return (short)(r >> 16);
}

__device__ inline unsigned cvt_pk_bf16(float lo, float hi) {
  unsigned w;
  asm("v_cvt_pk_bf16_f32 %0, %1, %2" : "=v"(w) : "v"(lo), "v"(hi));
  return w;
}

__device__ inline void async_load16(const void* g, void* l) {
  __builtin_amdgcn_global_load_lds(
      (const __attribute__((address_space(1))) void*)g,
      (__attribute__((address_space(3))) void*)l, 16, 0, 0);
}

// 16B-chunk swizzle within a 128B LDS row (8 chunks); row in [0,64)
__device__ inline int swz8(int r) { return (r & 3) | (((r >> 3) & 1) << 2); }

// ---------------- fp32 -> bf16 convert (X) ----------------
__global__ __launch_bounds__(256)
void cvt_bf16(const float* __restrict__ in, short* __restrict__ out) {
  const size_t i = (size_t)blockIdx.x * 256 + threadIdx.x;
  float4 v = ((const float4*)in)[i];
  bf16x4 o;
  o[0] = f2bf(v.x); o[1] = f2bf(v.y); o[2] = f2bf(v.z); o[3] = f2bf(v.w);
  ((bf16x4*)out)[i] = o;
}

// ---------------- W[k][n] fp32 -> Wt[n][k] bf16 (QKV packed + O) ----------------
__global__ __launch_bounds__(256)
void transpose_w4(const float* __restrict__ W0, const float* __restrict__ W1,
                  const float* __restrict__ W2, const float* __restrict__ W3,
                  short* __restrict__ Tqkv, short* __restrict__ To) {
  const float* W; short* T;
  switch (blockIdx.z) {
    case 0: W = W0; T = Tqkv; break;
    case 1: W = W1; T = Tqkv + (size_t)1024 * 1024; break;
    case 2: W = W2; T = Tqkv + (size_t)2048 * 1024; break;
    default: W = W3; T = To; break;
  }
  __shared__ float tile[32][36];
  const int tid = threadIdx.x;
  const int tx = tid & 7, ty = tid >> 3;
  const int k0 = blockIdx.y << 5, n0 = blockIdx.x << 5;
  float4 v = *(const float4*)&W[(size_t)(k0 + ty) * H_ + n0 + (tx << 2)];
  tile[ty][(tx << 2) + 0] = v.x;
  tile[ty][(tx << 2) + 1] = v.y;
  tile[ty][(tx << 2) + 2] = v.z;
  tile[ty][(tx << 2) + 3] = v.w;
  __syncthreads();
  bf16x4 o;
  o[0] = f2bf(tile[(tx << 2) + 0][ty]);
  o[1] = f2bf(tile[(tx << 2) + 1][ty]);
  o[2] = f2bf(tile[(tx << 2) + 2][ty]);
  o[3] = f2bf(tile[(tx << 2) + 3][ty]);
  *(bf16x4*)&T[(size_t)(n0 + ty) * H_ + k0 + (tx << 2)] = o;
}

// ---------------- fused QKV GEMM: [4096,1024] @ [1024,3072] ----------------
// 256x256 tile, 8 waves (2M x 4N), BK=32, 2-deep counted-vmcnt pipeline
// (T3/T4: raw s_barrier + s_waitcnt vmcnt(4), never drain to 0 mid-loop).
// LDS 64 KB static. Staging dest is PER-WAVE base (m104: wave-uniform base
// + lane*16) — wave wv owns rows 16*wv..+15 of each 128-row slab.
// No LDS swizzle: 64B rows already distribute b128 reads uniformly.
// Q (n<1024): bf16 head layout, pre-scaled by 0.125*log2(e).
// K: bf16 head layout. V: bf16 transposed [bh][d][S].
#define QKV_NT 32  // K-tiles of 32

__global__ __launch_bounds__(512)
void gemm_qkv(const short* __restrict__ A, const short* __restrict__ Bt,
              const float* __restrict__ bq, const float* __restrict__ bk,
              const float* __restrict__ bv, short* __restrict__ Qo,
              short* __restrict__ Ko, short* __restrict__ Vto) {
  __shared__ short A_lds[2][256][32];  // 16 KB per buf
  __shared__ short B_lds[2][256][32];
  const int tid = threadIdx.x;          // 0..511
  const int lane = tid & 63, wv = tid >> 6;
  const int l16 = lane & 15, lg = lane >> 4;
  const int wr = wv >> 2, wc = wv & 3;  // 2M x 4N wave grid
  // XCD swizzle: 192 blocks = 8 x 24 (bijective)
  const int swzb = (blockIdx.x & 7) * 24 + (blockIdx.x >> 3);
  const int bx = swzb % 12, by = swzb / 12;
  const int m0 = by << 8, n0 = bx << 8;
  const int K = H_;

  // staging: wave wv stages rows 128*i_ + 16*wv .. +15 (dest base per-wave);
  // lane -> row +(lane>>2), 16B chunk (lane&3)  [linear, matches DMA layout]
  const int srow = lane >> 2;
  const int sch  = lane & 3;

#define QKV_STAGE(buf, t_)                                                     \
  {                                                                            \
    const int k0_ = (t_) << 5;                                                 \
    _Pragma("unroll")                                                          \
    for (int i_ = 0; i_ < 2; ++i_) {                                           \
      const int r0_ = 128 * i_ + 16 * wv;                                      \
      async_load16(A + (size_t)(m0 + r0_ + srow) * K + k0_ + (sch << 3),       \
                   &A_lds[buf][r0_][0]);                                       \
      async_load16(Bt + (size_t)(n0 + r0_ + srow) * K + k0_ + (sch << 3),      \
                   &B_lds[buf][r0_][0]);                                       \
    }                                                                          \
  }

  f32x4 acc[8][4] = {};

  // prologue: tiles 0,1 into bufs 0,1 (4 loads each per wave)
  QKV_STAGE(0, 0)
  QKV_STAGE(1, 1)
  asm volatile("s_waitcnt vmcnt(4)" ::: "memory");  // own tile-0 loads complete
  __builtin_amdgcn_s_barrier();                     // => all of buf 0 complete
  __builtin_amdgcn_sched_barrier(0);

  for (int t = 0; t < QKV_NT; ++t) {
    const int cur = t & 1;
    bf16x8 af[8], bfr[4];
#pragma unroll
    for (int i = 0; i < 8; ++i)
      af[i] = *(const bf16x8*)&A_lds[cur][128 * wr + 16 * i + l16][8 * lg];
#pragma unroll
    for (int j = 0; j < 4; ++j)
      bfr[j] = *(const bf16x8*)&B_lds[cur][64 * wc + 16 * j + l16][8 * lg];
    __builtin_amdgcn_s_setprio(1);
#pragma unroll
    for (int i = 0; i < 8; ++i)
#pragma unroll
      for (int j = 0; j < 4; ++j)
        acc[i][j] = __builtin_amdgcn_mfma_f32_16x16x32_bf16(af[i], bfr[j], acc[i][j], 0, 0, 0);
    __builtin_amdgcn_s_setprio(0);
    __builtin_amdgcn_sched_barrier(0);
    __builtin_amdgcn_s_barrier();   // all waves done reading buf[cur]
    __builtin_amdgcn_sched_barrier(0);
    if (t + 2 < QKV_NT) {
      QKV_STAGE(cur, t + 2)         // refill freed buffer
      asm volatile("s_waitcnt vmcnt(4)" ::: "memory");  // tile t+1 complete
    } else {
      asm volatile("s_waitcnt vmcnt(0)" ::: "memory");
    }
    __builtin_amdgcn_s_barrier();   // publish buf[cur^1]
    __builtin_amdgcn_sched_barrier(0);
  }
#undef QKV_STAGE

  const int mt = n0 >> 10;  // 0=Q 1=K 2=V (uniform: 256-tiles don't straddle)
  const float* bias = (mt == 0) ? bq : (mt == 1 ? bk : bv);
  const float qs = (mt == 0) ? 0.125f * 1.4426950408889634f : 1.0f;

  if (mt < 2) {
    short* Out = (mt == 0) ? Qo : Ko;
#pragma unroll
    for (int i = 0; i < 8; ++i) {
#pragma unroll
      for (int j = 0; j < 4; ++j) {
        const int nl = (n0 & 1023) + 64 * wc + 16 * j + l16;
        const float bvl = bias[nl];
        const int h = nl >> 6, d = nl & 63;
#pragma unroll
        for (int r = 0; r < 4; ++r) {
          const int m = m0 + 128 * wr + 16 * i + 4 * lg + r;
          const int b = m >> 11, s = m & (S_ - 1);
          Out[(((size_t)(b * NH_ + h) * S_ + s) << 6) + d] =
              f2bf((acc[i][j][r] + bvl) * qs);
        }
      }
    }
  } else {
#pragma unroll
    for (int i = 0; i < 8; ++i) {
      const int mb = m0 + 128 * wr + 16 * i + 4 * lg;  // r=0..3 consecutive s
      const int b = mb >> 11, s = mb & (S_ - 1);
#pragma unroll
      for (int j = 0; j < 4; ++j) {
        const int nl = (n0 & 1023) + 64 * wc + 16 * j + l16;
        const float bvl = bias[nl];
        const int h = nl >> 6, d = nl & 63;
        bf16x4 pk;
#pragma unroll
        for (int r = 0; r < 4; ++r) pk[r] = f2bf(acc[i][j][r] + bvl);
        *(bf16x4*)&Vto[(((size_t)(b * NH_ + h) * HD_ + d) << 11) + s] = pk;
      }
    }
  }
}

// ---------------- O-projection GEMM: 64x128 tiles (512 blocks = 2/CU) ----------------
__global__ __launch_bounds__(256)
void gemm_o(const short* __restrict__ A, const short* __restrict__ Bt,
            const float* __restrict__ bias, float* __restrict__ C) {
  __shared__ short A_lds[2][64][32];   // 4 KB per buf
  __shared__ short B_lds[2][128][32];  // 8 KB per buf
  const int tid = threadIdx.x;
  const int lane = tid & 63, wv = tid >> 6;
  const int l16 = lane & 15, lg = lane >> 4;
  const int wr = wv >> 1, wc = wv & 1;
  const int swzb = (blockIdx.x & 7) * 64 + (blockIdx.x >> 3);  // 512 blocks bijective
  const int bx = swzb & 7, by = swzb >> 3;
  const int m0 = by << 6, n0 = bx << 7;
  const int K = H_;

  const int srow = lane >> 2, soff = (lane & 3) << 3;

  f32x4 acc[2][4] = {};

  // prologue: A (64 rows): 1 load/wave; B (128 rows): 2 loads/wave
  async_load16(A + (size_t)(m0 + 16 * wv + srow) * K + soff, &A_lds[0][16 * wv][0]);
#pragma unroll
  for (int i = 0; i < 2; ++i) {
    const int c = 2 * wv + i;
    async_load16(Bt + (size_t)(n0 + 16 * c + srow) * K + soff, &B_lds[0][16 * c][0]);
  }

  int cur = 0;
  for (int t = 0; t < K / 32; ++t) {
    __syncthreads();
    if (t + 1 < K / 32) {
      const int k0 = (t + 1) << 5;
      async_load16(A + (size_t)(m0 + 16 * wv + srow) * K + k0 + soff,
                   &A_lds[cur ^ 1][16 * wv][0]);
#pragma unroll
      for (int i = 0; i < 2; ++i) {
        const int c = 2 * wv + i;
        async_load16(Bt + (size_t)(n0 + 16 * c + srow) * K + k0 + soff,
                     &B_lds[cur ^ 1][16 * c][0]);
      }
    }
    bf16x8 af[2], bfr[4];
#pragma unroll
    for (int i = 0; i < 2; ++i)
      af[i] = *(const bf16x8*)&A_lds[cur][32 * wr + 16 * i + l16][8 * lg];
#pragma unroll
    for (int j = 0; j < 4; ++j)
      bfr[j] = *(const bf16x8*)&B_lds[cur][64 * wc + 16 * j + l16][8 * lg];
#pragma unroll
    for (int i = 0; i < 2; ++i)
#pragma unroll
      for (int j = 0; j < 4; ++j)
        acc[i][j] = __builtin_amdgcn_mfma_f32_16x16x32_bf16(af[i], bfr[j], acc[i][j], 0, 0, 0);
    cur ^= 1;
  }

#pragma unroll
  for (int i = 0; i < 2; ++i)
#pragma unroll
    for (int j = 0; j < 4; ++j) {
      const int n = n0 + 64 * wc + 16 * j + l16;
      const float bvl = bias[n];
#pragma unroll
      for (int r = 0; r < 4; ++r) {
        const int m = m0 + 32 * wr + 16 * i + 4 * lg + r;
        C[(size_t)m * H_ + n] = acc[i][j][r] + bvl;
      }
    }
}

// ---------------- Flash attention: swapped QK^T, in-register P ----------------
// (unchanged: KVB=128 as 2 subtiles, reg-staged T14, chunk-XOR swizzled
// slots, exp2-domain softmax, defer-max, setprio on MFMA clusters)
__global__ __launch_bounds__(256)
void attn_mfma(const short* __restrict__ Qg, const short* __restrict__ Kg,
               const short* __restrict__ Vtg, short* __restrict__ ctxb) {
  __shared__ short K_lds[2][2][64][64];  // [buf][half][kv][d], swizzled slots
  __shared__ short V_t[2][2][64][64];    // [buf][half][d][kv], swizzled slots

  const int tid  = threadIdx.x;
  const int lane = tid & 63;
  const int wv   = tid >> 6;
  const int l16  = lane & 15, lg = lane >> 4;

  const int swz = (blockIdx.x & 7) * 128 + (blockIdx.x >> 3);
  const int bh = swz >> 5, qb = swz & 31;

  const short* Qh = Qg + ((size_t)bh * S_ << 6);
  const short* Kh = Kg + ((size_t)bh * S_ << 6);
  const short* Vh = Vtg + ((size_t)bh << 6) * S_;  // [64][2048]

  const int q0 = qb * 64 + wv * 16;

  bf16x8 qf[2];
  qf[0] = *(const bf16x8*)&Qh[((size_t)(q0 + l16) << 6) + 8 * lg];
  qf[1] = *(const bf16x8*)&Qh[((size_t)(q0 + l16) << 6) + 8 * lg + 32];

  const int l16part = ((l16 >> 2) << 3) + (l16 & 3);  // K-row remap, lane part

  const int kr = tid >> 2;
  const int cb = (tid & 3) << 1;
  const int sz = swz8(kr);
  const int c1 = ((cb    ) ^ sz) << 3;
  const int c2 = ((cb + 1) ^ sz) << 3;

  f32x4 o[4] = {};
  float m_run = -1e30f, l_run = 0.f;

#pragma unroll
  for (int h = 0; h < 2; ++h) {
    const size_t kg = ((size_t)(64 * h + kr)) << 6;
    *(bf16x8*)&K_lds[0][h][kr][c1] = *(const bf16x8*)&Kh[kg + (cb << 3)];
    *(bf16x8*)&K_lds[0][h][kr][c2] = *(const bf16x8*)&Kh[kg + ((cb + 1) << 3)];
    const size_t vg = (size_t)kr * S_ + 64 * h;
    *(bf16x8*)&V_t[0][h][kr][c1]   = *(const bf16x8*)&Vh[vg + (cb << 3)];
    *(bf16x8*)&V_t[0][h][kr][c2]   = *(const bf16x8*)&Vh[vg + ((cb + 1) << 3)];
  }

  int cur = 0;
  for (int t = 0; t < S_ / 128; ++t) {
    bf16x8 nk[2][2], nv[2][2];
    const bool pre = (t + 1 < S_ / 128);
    if (pre) {
      const int kvn = (t + 1) * 128;
#pragma unroll
      for (int h = 0; h < 2; ++h) {
        const size_t kb = ((size_t)(kvn + 64 * h + kr)) << 6;
        nk[h][0] = *(const bf16x8*)&Kh[kb + (cb << 3)];
        nk[h][1] = *(const bf16x8*)&Kh[kb + ((cb + 1) << 3)];
        const size_t vb = (size_t)kr * S_ + kvn + 64 * h;
        nv[h][0] = *(const bf16x8*)&Vh[vb + (cb << 3)];
        nv[h][1] = *(const bf16x8*)&Vh[vb + ((cb + 1) << 3)];
      }
    }
    __syncthreads();

    f32x4 s[2][4] = {};
    __builtin_amdgcn_s_setprio(1);
#pragma unroll
    for (int h = 0; h < 2; ++h)
#pragma unroll
      for (int ks = 0; ks < 2; ++ks)
#pragma unroll
        for (int tt = 0; tt < 4; ++tt) {
          const int krow = ((tt >> 1) << 5) + ((tt & 1) << 2) + l16part;
          const int kch = (lg + 4 * ks) ^ swz8(krow);
          bf16x8 kf = *(const bf16x8*)&K_lds[cur][h][krow][kch << 3];
          s[h][tt] = __builtin_amdgcn_mfma_f32_16x16x32_bf16(kf, qf[ks], s[h][tt], 0, 0, 0);
        }
    __builtin_amdgcn_s_setprio(0);

    float pmax = -1e30f;
#pragma unroll
    for (int h = 0; h < 2; ++h)
#pragma unroll
      for (int tt = 0; tt < 4; ++tt)
        pmax = fmaxf(pmax, fmaxf(fmaxf(s[h][tt][0], s[h][tt][1]),
                                 fmaxf(s[h][tt][2], s[h][tt][3])));
    pmax = fmaxf(pmax, __shfl_xor(pmax, 16));
    pmax = fmaxf(pmax, __shfl_xor(pmax, 32));

    float p[2][4][4];
    float rs = 0.f;
    if (__any(pmax - m_run > 8.0f)) {
      const float mn = fmaxf(m_run, pmax);
      const float scl = __builtin_amdgcn_exp2f(m_run - mn);
      m_run = mn;
#pragma unroll
      for (int h = 0; h < 2; ++h)
#pragma unroll
        for (int tt = 0; tt < 4; ++tt)
#pragma unroll
          for (int r = 0; r < 4; ++r) {
            p[h][tt][r] = __builtin_amdgcn_exp2f(s[h][tt][r] - mn);
            rs += p[h][tt][r];
          }
      rs += __shfl_xor(rs, 16);
      rs += __shfl_xor(rs, 32);
      l_run = l_run * scl + rs;
      float sclr[4];
#pragma unroll
      for (int r = 0; r < 4; ++r) sclr[r] = __shfl(scl, 4 * lg + r);
#pragma unroll
      for (int tt = 0; tt < 4; ++tt)
#pragma unroll
        for (int r = 0; r < 4; ++r) o[tt][r] *= sclr[r];
    } else {
#pragma unroll
      for (int h = 0; h < 2; ++h)
#pragma unroll
        for (int tt = 0; tt < 4; ++tt)
#pragma unroll
          for (int r = 0; r < 4; ++r) {
            p[h][tt][r] = __builtin_amdgcn_exp2f(s[h][tt][r] - m_run);
            rs += p[h][tt][r];
          }
      rs += __shfl_xor(rs, 16);
      rs += __shfl_xor(rs, 32);
      l_run += rs;
    }

    unsigned w[2][4][2];
#pragma unroll
    for (int h = 0; h < 2; ++h)
#pragma unroll
      for (int tt = 0; tt < 4; ++tt) {
        w[h][tt][0] = cvt_pk_bf16(p[h][tt][0], p[h][tt][1]);
        w[h][tt][1] = cvt_pk_bf16(p[h][tt][2], p[h][tt][3]);
      }

    __builtin_amdgcn_s_setprio(1);
#pragma unroll
    for (int h = 0; h < 2; ++h)
#pragma unroll
      for (int ks = 0; ks < 2; ++ks) {
        i32x4 aw;
        aw[0] = (int)w[h][2 * ks][0];
        aw[1] = (int)w[h][2 * ks][1];
        aw[2] = (int)w[h][2 * ks + 1][0];
        aw[3] = (int)w[h][2 * ks + 1][1];
        const bf16x8 pf = __builtin_bit_cast(bf16x8, aw);
#pragma unroll
        for (int tt = 0; tt < 4; ++tt) {
          const int vrow = 16 * tt + l16;
          const int vch = (lg + 4 * ks) ^ swz8(vrow);
          bf16x8 vf = *(const bf16x8*)&V_t[cur][h][vrow][vch << 3];
          o[tt] = __builtin_amdgcn_mfma_f32_16x16x32_bf16(pf, vf, o[tt], 0, 0, 0);
        }
      }
    __builtin_amdgcn_s_setprio(0);

    if (pre) {
#pragma unroll
      for (int h = 0; h < 2; ++h) {
        *(bf16x8*)&K_lds[cur ^ 1][h][kr][c1] = nk[h][0];
        *(bf16x8*)&K_lds[cur ^ 1][h][kr][c2] = nk[h][1];
        *(bf16x8*)&V_t[cur ^ 1][h][kr][c1]   = nv[h][0];
        *(bf16x8*)&V_t[cur ^ 1][h][kr][c2]   = nv[h][1];
      }
    }
    cur ^= 1;
  }

  float invr[4];
#pragma unroll
  for (int r = 0; r < 4; ++r) invr[r] = 1.f / __shfl(l_run, 4 * lg + r);
  const int b = bh >> 4, h = bh & 15;
#pragma unroll
  for (int r = 0; r < 4; ++r) {
    const int q = q0 + 4 * lg + r;
#pragma unroll
    for (int tt = 0; tt < 4; ++tt)
      ctxb[(((size_t)(b * S_ + q) * NH_ + h) << 6) + 16 * tt + l16] =
          f2bf(o[tt][r] * invr[r]);
  }
}

// ---------------- residual + LayerNorm ----------------
__global__ __launch_bounds__(256)
void resid_ln(const float* __restrict__ attn_out, const float* __restrict__ hs,
              const float* __restrict__ gamma, const float* __restrict__ beta,
              float* __restrict__ out) {
  __shared__ float reds[4], reds2[4];
  const int row = blockIdx.x;
  const int tid = threadIdx.x;
  const float4* a4 = (const float4*)(attn_out + ((size_t)row << 10));
  const float4* h4 = (const float4*)(hs + ((size_t)row << 10));
  float4 a = a4[tid], h = h4[tid];
  float e0 = a.x + h.x, e1 = a.y + h.y, e2 = a.z + h.z, e3 = a.w + h.w;
  float s  = e0 + e1 + e2 + e3;
  float sq = e0 * e0 + e1 * e1 + e2 * e2 + e3 * e3;
  s = waveReduceSum(s);
  sq = waveReduceSum(sq);
  const int lane = tid & 63, wave = tid >> 6;
  if (lane == 0) { reds[wave] = s; reds2[wave] = sq; }
  __syncthreads();
  const float S1 = reds[0] + reds[1] + reds[2] + reds[3];
  const float S2 = reds2[0] + reds2[1] + reds2[2] + reds2[3];
  const float mu = S1 * (1.f / H_);
  const float var = S2 * (1.f / H_) - mu * mu;
  const float rstd = rsqrtf(var + 1e-12f);
  const float4 g = ((const float4*)gamma)[tid];
  const float4 bb = ((const float4*)beta)[tid];
  float4 o;
  o.x = (e0 - mu) * rstd * g.x + bb.x;
  o.y = (e1 - mu) * rstd * g.y + bb.y;
  o.z = (e2 - mu) * rstd * g.z + bb.z;
  o.w = (e3 - mu) * rstd * g.w + bb.w;
  ((float4*)(out + ((size_t)row << 10)))[tid] = o;
}

extern "C" void kernel_launch(void* const* d_in, const int* in_sizes, int n_in,
                              void* d_out, int out_size, void* d_ws, size_t ws_size,
                              hipStream_t stream) {
  const float* X     = (const float*)d_in[0];
  const float* Wq    = (const float*)d_in[1];
  const float* bq    = (const float*)d_in[2];
  const float* Wk    = (const float*)d_in[3];
  const float* bk    = (const float*)d_in[4];
  const float* Wv    = (const float*)d_in[5];
  const float* bv    = (const float*)d_in[6];
  const float* Wo    = (const float*)d_in[7];
  const float* bo    = (const float*)d_in[8];
  const float* gamma = (const float*)d_in[9];
  const float* beta  = (const float*)d_in[10];
  float* out = (float*)d_out;

  // workspace layout (peak 40 MB)
  char* ws = (char*)d_ws;
  short* Xbf  = (short*)ws;                        // 8 MB [M][H] bf16
  short* Wqkv = (short*)(ws + ( 8u << 20));        // 6 MB [3072][1024] bf16
  short* Wto  = (short*)(ws + (14u << 20));        // 2 MB [1024][1024] bf16
  short* Qbf  = (short*)(ws + (16u << 20));        // 8 MB [bh][s][64] (pre-scaled)
  short* Kbf  = (short*)(ws + (24u << 20));        // 8 MB [bh][s][64]
  short* Vt   = (short*)(ws + (32u << 20));        // 8 MB [bh][d][S] (transposed)
  short* ctxb = Xbf;                               // ctx bf16 overwrites Xbf (dead)
  float* attn = (float*)(ws + (16u << 20));        // fp32, overwrites Q/K (dead)

  dim3 blk(256);
  hipLaunchKernelGGL(cvt_bf16, dim3((M_ * H_) / 1024), blk, 0, stream, X, Xbf);
  hipLaunchKernelGGL(transpose_w4, dim3(32, 32, 4), blk, 0, stream,
                     Wq, Wk, Wv, Wo, Wqkv, Wto);
  hipLaunchKernelGGL(gemm_qkv, dim3(192), dim3(512), 0, stream,
                     Xbf, Wqkv, bq, bk, bv, Qbf, Kbf, Vt);
  hipLaunchKernelGGL(attn_mfma, dim3(1024), blk, 0, stream, Qbf, Kbf, Vt, ctxb);
  hipLaunchKernelGGL(gemm_o, dim3(512), blk, 0, stream, ctxb, Wto, bo, attn);
  hipLaunchKernelGGL(resid_ln, dim3(M_), blk, 0, stream, attn, X, gamma, beta, out);
}